// Round 6
// baseline (634.069 us; speedup 1.0000x reference)
//
#include <hip/hip_runtime.h>
#include <stdint.h>

typedef unsigned short u16;
typedef __attribute__((ext_vector_type(8))) short short8;
typedef __attribute__((ext_vector_type(4))) float f32x4;

#define N_NODES 100000
#define RREL    3
#define NEDGE   1600000
#define NPAIR   1024
#define NSEG    (RREL * N_NODES)

// binned CSR build params
#define EPB   4096
#define NBLK  ((NEDGE + EPB - 1) / EPB)   // 391
#define DPB   512                          // dsts per bin (dst >> 9)
#define NBIN  ((N_NODES + DPB - 1) / DPB)  // 196
#define LSEG  (DPB * RREL)                 // 1536 local segments per bin

// ---------- bf16 helpers ----------
__device__ __forceinline__ float bf2f(u16 h) {
    union { unsigned int u; float f; } c; c.u = ((unsigned int)h) << 16; return c.f;
}
__device__ __forceinline__ u16 f2bf(float f) {
    union { float f; unsigned int u; } c; c.f = f;
    unsigned int u = c.u;
    u += 0x7fffu + ((u >> 16) & 1u);   // round-to-nearest-even
    return (u16)(u >> 16);
}

// ---------- cast f32 -> bf16, 4 elems/thread ----------
__global__ __launch_bounds__(256) void cast_kernel(const float* __restrict__ in,
                                                   u16* __restrict__ out, int n4) {
    int i = blockIdx.x * 256 + threadIdx.x;
    if (i >= n4) return;
    float4 v = ((const float4*)in)[i];
    uint2 o;
    o.x = ((unsigned int)f2bf(v.y) << 16) | (unsigned int)f2bf(v.x);
    o.y = ((unsigned int)f2bf(v.w) << 16) | (unsigned int)f2bf(v.z);
    ((uint2*)out)[i] = o;
}

// ========== CSR build: binned counting sort, no global atomics ==========

// P1: per-block histogram over dst-bins -> bc[bin * NBLK + blk]
__global__ __launch_bounds__(256) void p1_count(const int* __restrict__ ed,
                                                int* __restrict__ bc) {
    __shared__ int h[NBIN];
    int t = threadIdx.x, b = blockIdx.x;
    for (int i = t; i < NBIN; i += 256) h[i] = 0;
    __syncthreads();
    int e0 = b * EPB;
    int e1 = e0 + EPB; if (e1 > NEDGE) e1 = NEDGE;
    for (int i = e0 + t; i < e1; i += 256)
        atomicAdd(&h[ed[i] >> 9], 1);
    __syncthreads();
    for (int i = t; i < NBIN; i += 256) bc[i * NBLK + b] = h[i];
}

// P2: single-block exclusive scan of bc (NBIN*NBLK elements, bin-major)
__global__ __launch_bounds__(1024) void p2_scan(const int* __restrict__ bc,
                                                int* __restrict__ sc) {
    const int TOT = NBIN * NBLK;
    const int CH = (TOT + 1023) / 1024;
    int t = threadIdx.x;
    int base = t * CH;
    int s = 0;
    for (int i = 0; i < CH; ++i) { int f = base + i; if (f < TOT) s += bc[f]; }
    int lane = t & 63, wv = t >> 6;   // 16 waves
    int incl = s;
    #pragma unroll
    for (int d = 1; d < 64; d <<= 1) { int v = __shfl_up(incl, d); if (lane >= d) incl += v; }
    __shared__ int wtot[16];
    if (lane == 63) wtot[wv] = incl;
    __syncthreads();
    int wpre = 0;
    #pragma unroll
    for (int i = 0; i < 16; ++i) if (i < wv) wpre += wtot[i];
    int excl = wpre + incl - s;
    for (int i = 0; i < CH; ++i) {
        int f = base + i;
        if (f < TOT) { sc[f] = excl; excl += bc[f]; }
    }
}

// P3: write packed edges grouped by bin. packed = (src << 11) | (dstlow*3 + r)
__global__ __launch_bounds__(256) void p3_binscatter(const int* __restrict__ es,
                                                     const int* __restrict__ ed,
                                                     const int* __restrict__ et,
                                                     const int* __restrict__ sc,
                                                     unsigned int* __restrict__ binned) {
    __shared__ int pos[NBIN];
    int t = threadIdx.x, b = blockIdx.x;
    for (int i = t; i < NBIN; i += 256) pos[i] = sc[i * NBLK + b];
    __syncthreads();
    int e0 = b * EPB;
    int e1 = e0 + EPB; if (e1 > NEDGE) e1 = NEDGE;
    for (int i = e0 + t; i < e1; i += 256) {
        int d = ed[i];
        int bin = d >> 9;
        unsigned int pk = ((unsigned int)es[i] << 11) | (unsigned int)((d & 511) * 3 + et[i]);
        int p = atomicAdd(&pos[bin], 1);
        binned[p] = pk;
    }
}

// P4: per-bin CSR finalize. seg = dst*3 + r (dst-major, dense in [0, 3N)).
__global__ __launch_bounds__(256) void p4_finalize(const unsigned int* __restrict__ binned,
                                                   const int* __restrict__ sc,
                                                   int* __restrict__ seg_start,
                                                   int* __restrict__ cnt,
                                                   int* __restrict__ sorted_src) {
    __shared__ int h[LSEG];
    __shared__ int cur[LSEG];
    __shared__ int wtot4[4];
    int t = threadIdx.x, bin = blockIdx.x;
    for (int i = t; i < LSEG; i += 256) h[i] = 0;
    __syncthreads();
    int eb = sc[bin * NBLK];
    int ee = (bin == NBIN - 1) ? NEDGE : sc[(bin + 1) * NBLK];
    for (int i = eb + t; i < ee; i += 256)
        atomicAdd(&h[binned[i] & 2047u], 1);
    __syncthreads();
    // exclusive scan of h[0..LSEG): thread t owns entries [t*6, t*6+6)
    int i6 = t * 6;
    int s = 0;
    #pragma unroll
    for (int i = 0; i < 6; ++i) s += h[i6 + i];
    int lane = t & 63, wv = t >> 6;
    int incl = s;
    #pragma unroll
    for (int d = 1; d < 64; d <<= 1) { int v = __shfl_up(incl, d); if (lane >= d) incl += v; }
    if (lane == 63) wtot4[wv] = incl;
    __syncthreads();
    int wpre = 0;
    #pragma unroll
    for (int i = 0; i < 4; ++i) if (i < wv) wpre += wtot4[i];
    int run = wpre + incl - s;   // exclusive base for this thread's 6 entries
    int segbase = bin * LSEG;
    #pragma unroll
    for (int i = 0; i < 6; ++i) {
        int ls = i6 + i;
        int c = h[ls];
        int seg = segbase + ls;
        if (seg < NSEG) { seg_start[seg] = eb + run; cnt[seg] = c; }
        cur[ls] = run;
        run += c;
    }
    __syncthreads();
    for (int i = eb + t; i < ee; i += 256) {
        unsigned int u = binned[i];
        int ls = (int)(u & 2047u);
        int p = atomicAdd(&cur[ls], 1);
        sorted_src[eb + p] = (int)(u >> 11);
    }
}

// ---------- per-segment mean of bf16 (N,128) rows; one wave per seg=dst*3+r ----------
__global__ __launch_bounds__(256) void seg_mean(const unsigned int* __restrict__ Xu,  // (N,64) uint = bf16x2
                                                const int* __restrict__ seg_start,
                                                const int* __restrict__ cnt,
                                                const int* __restrict__ sorted_src,
                                                u16* __restrict__ Abuf) {
    int wid  = (blockIdx.x * 256 + threadIdx.x) >> 6;
    int lane = threadIdx.x & 63;
    if (wid >= NSEG) return;
    int dst = wid / 3;
    int r   = wid - dst * 3;
    int c  = cnt[wid];
    int st = seg_start[wid];
    float a0 = 0.f, a1 = 0.f;
    int e = 0;
    for (; e + 4 <= c; e += 4) {
        int s0 = sorted_src[st + e + 0];
        int s1 = sorted_src[st + e + 1];
        int s2 = sorted_src[st + e + 2];
        int s3 = sorted_src[st + e + 3];
        unsigned int v0 = Xu[(size_t)s0 * 64 + lane];
        unsigned int v1 = Xu[(size_t)s1 * 64 + lane];
        unsigned int v2 = Xu[(size_t)s2 * 64 + lane];
        unsigned int v3 = Xu[(size_t)s3 * 64 + lane];
        a0 += bf2f((u16)(v0 & 0xffffu)) + bf2f((u16)(v1 & 0xffffu))
            + bf2f((u16)(v2 & 0xffffu)) + bf2f((u16)(v3 & 0xffffu));
        a1 += bf2f((u16)(v0 >> 16)) + bf2f((u16)(v1 >> 16))
            + bf2f((u16)(v2 >> 16)) + bf2f((u16)(v3 >> 16));
    }
    for (; e < c; ++e) {
        int src = sorted_src[st + e];
        unsigned int v = Xu[(size_t)src * 64 + lane];
        a0 += bf2f((u16)(v & 0xffffu));
        a1 += bf2f((u16)(v >> 16));
    }
    float sc = 1.0f / (float)(c > 0 ? c : 1);
    unsigned int o = ((unsigned int)f2bf(a1 * sc) << 16) | (unsigned int)f2bf(a0 * sc);
    ((unsigned int*)Abuf)[(size_t)dst * 192 + r * 64 + lane] = o;
}

// ---------- weight transpose: f32 (512 x BN) k-major -> bf16 Wt (BN x 512) n-major ----------
template <int BN>
__global__ __launch_bounds__(256) void transpose_w(const float* __restrict__ Wrel,
                                                   const float* __restrict__ Wroot,
                                                   u16* __restrict__ Wt) {
    int idx = blockIdx.x * 256 + threadIdx.x;
    if (idx >= BN * 512) return;
    int n = idx >> 9;
    int k = idx & 511;
    float v = (k < 384) ? Wrel[(size_t)k * BN + n] : Wroot[(size_t)(k - 384) * BN + n];
    Wt[idx] = f2bf(v);
}

// ---------- fused GEMM: Out(M,BN) = [Alo(M,384) | Ahi(M,128)]_bf16 @ Wt^T + bias ----------
template <int BN, bool RELU, bool OUTF32>
__global__ __launch_bounds__(256) void gemm_fused(const u16* __restrict__ Alo,
                                                  const u16* __restrict__ Ahi,
                                                  const u16* __restrict__ Wt,
                                                  const float* __restrict__ bias,
                                                  void* __restrict__ OutV) {
    constexpr int M = N_NODES;
    constexpr int BM = 128, BK = 32, KTOT = 512, KLO = 384;
    __shared__ __align__(16) u16 As[BM * BK];
    __shared__ __align__(16) u16 Bs[BN * BK];
    const int t = threadIdx.x;
    const int w = t >> 6, l = t & 63;
    const int bm = blockIdx.x * BM;
    constexpr int WN  = (BN == 128) ? 2 : 1;
    constexpr int WTM = (BN == 128) ? 64 : 32;
    constexpr int WTN = 64;
    constexpr int MI = WTM / 16, NI = WTN / 16;
    const int wm = w / WN, wn = w % WN;
    const int q = l >> 4, lm = l & 15;   // quad, intra-16 index

    f32x4 acc[MI][NI] = {};

    const int ar = t >> 2;            // 0..63
    const int ac = (t & 3) * 8;       // 0,8,16,24

    for (int kt = 0; kt < KTOT / BK; ++kt) {
        const int k0 = kt * BK;
        const u16* base; int stride, kk;
        if (k0 < KLO) { base = Alo; stride = 384; kk = k0; }
        else          { base = Ahi; stride = 128; kk = k0 - KLO; }
        short8 va[2];
        #pragma unroll
        for (int i = 0; i < 2; ++i) {
            int gr = bm + i * 64 + ar; if (gr >= M) gr = M - 1;
            va[i] = *(const short8*)(base + (size_t)gr * stride + kk + ac);
        }
        short8 vb[BN / 64];
        #pragma unroll
        for (int i = 0; i < BN / 64; ++i) {
            int rn = i * 64 + ar;
            vb[i] = *(const short8*)(Wt + (size_t)rn * KTOT + k0 + ac);
        }
        __syncthreads();   // previous iteration done reading LDS
        #pragma unroll
        for (int i = 0; i < 2; ++i)
            *(short8*)&As[(i * 64 + ar) * BK + ac] = va[i];
        #pragma unroll
        for (int i = 0; i < BN / 64; ++i)
            *(short8*)&Bs[(i * 64 + ar) * BK + ac] = vb[i];
        __syncthreads();
        short8 fa[MI], fb[NI];
        #pragma unroll
        for (int mi = 0; mi < MI; ++mi)
            fa[mi] = *(const short8*)&As[(wm * WTM + mi * 16 + lm) * BK + q * 8];
        #pragma unroll
        for (int ni = 0; ni < NI; ++ni)
            fb[ni] = *(const short8*)&Bs[(wn * WTN + ni * 16 + lm) * BK + q * 8];
        #pragma unroll
        for (int mi = 0; mi < MI; ++mi)
            #pragma unroll
            for (int ni = 0; ni < NI; ++ni)
                acc[mi][ni] = __builtin_amdgcn_mfma_f32_16x16x32_bf16(
                    fa[mi], fb[ni], acc[mi][ni], 0, 0, 0);
    }
    // epilogue: C/D layout col=lane&15, row=q*4+reg
    #pragma unroll
    for (int mi = 0; mi < MI; ++mi) {
        #pragma unroll
        for (int ni = 0; ni < NI; ++ni) {
            int gc = wn * WTN + ni * 16 + lm;
            float bv = bias[gc];
            #pragma unroll
            for (int rg = 0; rg < 4; ++rg) {
                int gr = bm + wm * WTM + mi * 16 + q * 4 + rg;
                if (gr < M) {
                    float v = acc[mi][ni][rg] + bv;
                    if (RELU) v = fmaxf(v, 0.0f);
                    if (OUTF32) ((float*)OutV)[(size_t)gr * BN + gc] = v;
                    else        ((u16*)OutV)[(size_t)gr * BN + gc] = f2bf(v);
                }
            }
        }
    }
}

// ---------- final pair MLP: tanh(concat(node[nest],node[food]) @ fcW + fcb), all f32 ----------
__global__ __launch_bounds__(128) void pair_mlp(const float* __restrict__ node,
                                                const int* __restrict__ nest,
                                                const int* __restrict__ food,
                                                const float* __restrict__ fcW,
                                                const float* __restrict__ fcb,
                                                float* __restrict__ out) {
    int p = blockIdx.x;
    int t = threadIdx.x;
    __shared__ float pv[128];
    int n0 = nest[p], n1 = food[p];
    if ((unsigned)n0 >= (unsigned)N_NODES) n0 = 0;
    if ((unsigned)n1 >= (unsigned)N_NODES) n1 = 0;
    if (t < 64) pv[t] = node[(size_t)n0 * 64 + t];
    else        pv[t] = node[(size_t)n1 * 64 + (t - 64)];
    __syncthreads();
    float s = fcb[t];
    #pragma unroll 4
    for (int k = 0; k < 128; ++k)
        s += pv[k] * fcW[k * 128 + t];
    out[(size_t)p * 128 + t] = tanhf(s);
}

extern "C" void kernel_launch(void* const* d_in, const int* in_sizes, int n_in,
                              void* d_out, int out_size, void* d_ws, size_t ws_size,
                              hipStream_t stream) {
    const float* x    = (const float*)d_in[0];
    const int* esrc   = (const int*)d_in[1];
    const int* edst   = (const int*)d_in[2];
    const int* etyp   = (const int*)d_in[3];
    // d_in[4] edge_attr: dead code in reference
    const int* nest   = (const int*)d_in[5];
    const int* food   = (const int*)d_in[6];
    const float* Wrel1  = (const float*)d_in[7];
    const float* Wroot1 = (const float*)d_in[8];
    const float* b1     = (const float*)d_in[9];
    const float* Wrel2  = (const float*)d_in[10];
    const float* Wroot2 = (const float*)d_in[11];
    const float* b2     = (const float*)d_in[12];
    const float* fcW    = (const float*)d_in[13];
    const float* fcb    = (const float*)d_in[14];
    float* out = (float*)d_out;

    // workspace layout (256B aligned chunks)
    char* ws = (char*)d_ws;
    size_t off = 0;
    auto alloc_b = [&](size_t bytes) -> void* {
        void* p = ws + off;
        off += (bytes + 255) & ~(size_t)255;
        return p;
    };
    int* bc          = (int*)alloc_b((size_t)NBIN * NBLK * 4);
    int* sc          = (int*)alloc_b((size_t)NBIN * NBLK * 4);
    unsigned int* bn = (unsigned int*)alloc_b((size_t)NEDGE * 4);
    int* seg_start   = (int*)alloc_b((size_t)NSEG * 4);
    int* cnt         = (int*)alloc_b((size_t)NSEG * 4);
    int* sorted_src  = (int*)alloc_b((size_t)NEDGE * 4);
    u16* Wt1         = (u16*)alloc_b((size_t)128 * 512 * 2);
    u16* Wt2         = (u16*)alloc_b((size_t)64 * 512 * 2);
    u16* xb          = (u16*)alloc_b((size_t)N_NODES * 128 * 2);   // bf16(x)
    u16* Abuf        = (u16*)alloc_b((size_t)N_NODES * 384 * 2);   // bf16 agg
    u16* h1          = (u16*)alloc_b((size_t)N_NODES * 128 * 2);   // bf16
    float* node      = (float*)alloc_b((size_t)N_NODES * 64 * 4);  // f32

    // CSR build: binned counting sort (no global atomics)
    p1_count<<<NBLK, 256, 0, stream>>>(edst, bc);
    p2_scan<<<1, 1024, 0, stream>>>(bc, sc);
    p3_binscatter<<<NBLK, 256, 0, stream>>>(esrc, edst, etyp, sc, bn);
    p4_finalize<<<NBIN, 256, 0, stream>>>(bn, sc, seg_start, cnt, sorted_src);

    // weight transposes (f32 -> bf16 n-major)
    transpose_w<128><<<(128 * 512) / 256, 256, 0, stream>>>(Wrel1, Wroot1, Wt1);
    transpose_w<64><<<(64 * 512) / 256, 256, 0, stream>>>(Wrel2, Wroot2, Wt2);

    // cast x -> bf16 (also the gather source for layer-1 aggregation)
    cast_kernel<<<(N_NODES * 128 / 4 + 255) / 256, 256, 0, stream>>>(x, xb, N_NODES * 128 / 4);

    const int segBlocks  = (NSEG * 64) / 256;            // 75000
    const int gemmBlocks = (N_NODES + 127) / 128;        // 782

    // layer 1: agg(xb) -> Abuf ; [Abuf|xb] @ Wt1 + b1, relu -> h1 (bf16)
    seg_mean<<<segBlocks, 256, 0, stream>>>((const unsigned int*)xb, seg_start, cnt, sorted_src, Abuf);
    gemm_fused<128, true, false><<<gemmBlocks, 256, 0, stream>>>(Abuf, xb, Wt1, b1, h1);

    // layer 2: agg(h1) -> Abuf ; [Abuf|h1] @ Wt2 + b2 -> node (f32)
    seg_mean<<<segBlocks, 256, 0, stream>>>((const unsigned int*)h1, seg_start, cnt, sorted_src, Abuf);
    gemm_fused<64, false, true><<<gemmBlocks, 256, 0, stream>>>(Abuf, h1, Wt2, b2, node);

    // pair MLP (f32)
    pair_mlp<<<NPAIR, 128, 0, stream>>>(node, nest, food, fcW, fcb, out);
}

// Round 7
// 487.697 us; speedup vs baseline: 1.3001x; 1.3001x over previous
//
#include <hip/hip_runtime.h>
#include <stdint.h>

typedef unsigned short u16;
typedef __attribute__((ext_vector_type(8))) short short8;
typedef __attribute__((ext_vector_type(4))) float f32x4;

#define N_NODES 100000
#define RREL    3
#define NEDGE   1600000
#define NPAIR   1024
#define NSEG    (RREL * N_NODES)

// binned CSR build params
#define EPB   4096
#define NBLK  ((NEDGE + EPB - 1) / EPB)   // 391
#define DPB   512                          // dsts per bin (dst >> 9)
#define NBIN  ((N_NODES + DPB - 1) / DPB)  // 196
#define LSEG  (DPB * RREL)                 // 1536 local segments per bin

// ---------- bf16 helpers ----------
__device__ __forceinline__ float bf2f(u16 h) {
    union { unsigned int u; float f; } c; c.u = ((unsigned int)h) << 16; return c.f;
}
__device__ __forceinline__ u16 f2bf(float f) {
    union { float f; unsigned int u; } c; c.f = f;
    unsigned int u = c.u;
    u += 0x7fffu + ((u >> 16) & 1u);   // round-to-nearest-even
    return (u16)(u >> 16);
}

// ---------- cast f32 -> bf16, 4 elems/thread ----------
__global__ __launch_bounds__(256) void cast_kernel(const float* __restrict__ in,
                                                   u16* __restrict__ out, int n4) {
    int i = blockIdx.x * 256 + threadIdx.x;
    if (i >= n4) return;
    float4 v = ((const float4*)in)[i];
    uint2 o;
    o.x = ((unsigned int)f2bf(v.y) << 16) | (unsigned int)f2bf(v.x);
    o.y = ((unsigned int)f2bf(v.w) << 16) | (unsigned int)f2bf(v.z);
    ((uint2*)out)[i] = o;
}

// ========== CSR build: binned counting sort, no global atomics ==========

// P1: per-block histogram over dst-bins -> bc[bin * NBLK + blk]
__global__ __launch_bounds__(256) void p1_count(const int* __restrict__ ed,
                                                int* __restrict__ bc) {
    __shared__ int h[NBIN];
    int t = threadIdx.x, b = blockIdx.x;
    for (int i = t; i < NBIN; i += 256) h[i] = 0;
    __syncthreads();
    int e0 = b * EPB;
    int e1 = e0 + EPB; if (e1 > NEDGE) e1 = NEDGE;
    for (int i = e0 + t; i < e1; i += 256)
        atomicAdd(&h[ed[i] >> 9], 1);
    __syncthreads();
    for (int i = t; i < NBIN; i += 256) bc[i * NBLK + b] = h[i];
}

// P2a: per-bin scan of its 391 block-counts (one block per bin).
// sc[bin*NBLK + j] = bin-LOCAL exclusive prefix; bt[bin] = bin total.
__global__ __launch_bounds__(512) void p2a_binscan(const int* __restrict__ bc,
                                                   int* __restrict__ sc,
                                                   int* __restrict__ bt) {
    __shared__ int wtot[8];
    int t = threadIdx.x, bin = blockIdx.x;
    int v = (t < NBLK) ? bc[bin * NBLK + t] : 0;
    int lane = t & 63, wv = t >> 6;
    int incl = v;
    #pragma unroll
    for (int d = 1; d < 64; d <<= 1) { int u = __shfl_up(incl, d); if (lane >= d) incl += u; }
    if (lane == 63) wtot[wv] = incl;
    __syncthreads();
    int wpre = 0;
    #pragma unroll
    for (int i = 0; i < 8; ++i) if (i < wv) wpre += wtot[i];
    if (t < NBLK) sc[bin * NBLK + t] = wpre + incl - v;
    if (t == 511) bt[bin] = wpre + incl;   // total of all 391 (tail lanes add 0)
}

// P2b: scan bin totals (196) -> bb[bin] global base; bb[NBIN] = NEDGE.
__global__ __launch_bounds__(256) void p2b_totscan(const int* __restrict__ bt,
                                                   int* __restrict__ bb) {
    __shared__ int wtot[4];
    int t = threadIdx.x;
    int v = (t < NBIN) ? bt[t] : 0;
    int lane = t & 63, wv = t >> 6;
    int incl = v;
    #pragma unroll
    for (int d = 1; d < 64; d <<= 1) { int u = __shfl_up(incl, d); if (lane >= d) incl += u; }
    if (lane == 63) wtot[wv] = incl;
    __syncthreads();
    int wpre = 0;
    #pragma unroll
    for (int i = 0; i < 4; ++i) if (i < wv) wpre += wtot[i];
    if (t < NBIN) bb[t] = wpre + incl - v;
    if (t == 0) bb[NBIN] = NEDGE;
}

// P3: write packed edges grouped by bin. packed = (src << 11) | (dstlow*3 + r)
__global__ __launch_bounds__(256) void p3_binscatter(const int* __restrict__ es,
                                                     const int* __restrict__ ed,
                                                     const int* __restrict__ et,
                                                     const int* __restrict__ sc,
                                                     const int* __restrict__ bb,
                                                     unsigned int* __restrict__ binned) {
    __shared__ int pos[NBIN];
    int t = threadIdx.x, b = blockIdx.x;
    for (int i = t; i < NBIN; i += 256) pos[i] = bb[i] + sc[i * NBLK + b];
    __syncthreads();
    int e0 = b * EPB;
    int e1 = e0 + EPB; if (e1 > NEDGE) e1 = NEDGE;
    for (int i = e0 + t; i < e1; i += 256) {
        int d = ed[i];
        int bin = d >> 9;
        unsigned int pk = ((unsigned int)es[i] << 11) | (unsigned int)((d & 511) * 3 + et[i]);
        int p = atomicAdd(&pos[bin], 1);
        binned[p] = pk;
    }
}

// P4: per-bin CSR finalize. seg = dst*3 + r (dst-major, dense in [0, 3N)).
__global__ __launch_bounds__(256) void p4_finalize(const unsigned int* __restrict__ binned,
                                                   const int* __restrict__ bb,
                                                   int* __restrict__ seg_start,
                                                   int* __restrict__ cnt,
                                                   int* __restrict__ sorted_src) {
    __shared__ int h[LSEG];
    __shared__ int cur[LSEG];
    __shared__ int wtot4[4];
    int t = threadIdx.x, bin = blockIdx.x;
    for (int i = t; i < LSEG; i += 256) h[i] = 0;
    __syncthreads();
    int eb = bb[bin];
    int ee = bb[bin + 1];
    for (int i = eb + t; i < ee; i += 256)
        atomicAdd(&h[binned[i] & 2047u], 1);
    __syncthreads();
    // exclusive scan of h[0..LSEG): thread t owns entries [t*6, t*6+6)
    int i6 = t * 6;
    int s = 0;
    #pragma unroll
    for (int i = 0; i < 6; ++i) s += h[i6 + i];
    int lane = t & 63, wv = t >> 6;
    int incl = s;
    #pragma unroll
    for (int d = 1; d < 64; d <<= 1) { int v = __shfl_up(incl, d); if (lane >= d) incl += v; }
    if (lane == 63) wtot4[wv] = incl;
    __syncthreads();
    int wpre = 0;
    #pragma unroll
    for (int i = 0; i < 4; ++i) if (i < wv) wpre += wtot4[i];
    int run = wpre + incl - s;   // exclusive base for this thread's 6 entries
    int segbase = bin * LSEG;
    #pragma unroll
    for (int i = 0; i < 6; ++i) {
        int ls = i6 + i;
        int c = h[ls];
        int seg = segbase + ls;
        if (seg < NSEG) { seg_start[seg] = eb + run; cnt[seg] = c; }
        cur[ls] = run;
        run += c;
    }
    __syncthreads();
    for (int i = eb + t; i < ee; i += 256) {
        unsigned int u = binned[i];
        int ls = (int)(u & 2047u);
        int p = atomicAdd(&cur[ls], 1);
        sorted_src[eb + p] = (int)(u >> 11);
    }
}

// ---------- per-segment mean of bf16 (N,128) rows; one wave per seg=dst*3+r ----------
__global__ __launch_bounds__(256) void seg_mean(const unsigned int* __restrict__ Xu,  // (N,64) uint = bf16x2
                                                const int* __restrict__ seg_start,
                                                const int* __restrict__ cnt,
                                                const int* __restrict__ sorted_src,
                                                u16* __restrict__ Abuf) {
    int wid  = (blockIdx.x * 256 + threadIdx.x) >> 6;
    int lane = threadIdx.x & 63;
    if (wid >= NSEG) return;
    int dst = wid / 3;
    int r   = wid - dst * 3;
    int c  = cnt[wid];
    int st = seg_start[wid];
    float a0 = 0.f, a1 = 0.f;
    int e = 0;
    for (; e + 4 <= c; e += 4) {
        int s0 = sorted_src[st + e + 0];
        int s1 = sorted_src[st + e + 1];
        int s2 = sorted_src[st + e + 2];
        int s3 = sorted_src[st + e + 3];
        unsigned int v0 = Xu[(size_t)s0 * 64 + lane];
        unsigned int v1 = Xu[(size_t)s1 * 64 + lane];
        unsigned int v2 = Xu[(size_t)s2 * 64 + lane];
        unsigned int v3 = Xu[(size_t)s3 * 64 + lane];
        a0 += bf2f((u16)(v0 & 0xffffu)) + bf2f((u16)(v1 & 0xffffu))
            + bf2f((u16)(v2 & 0xffffu)) + bf2f((u16)(v3 & 0xffffu));
        a1 += bf2f((u16)(v0 >> 16)) + bf2f((u16)(v1 >> 16))
            + bf2f((u16)(v2 >> 16)) + bf2f((u16)(v3 >> 16));
    }
    for (; e < c; ++e) {
        int src = sorted_src[st + e];
        unsigned int v = Xu[(size_t)src * 64 + lane];
        a0 += bf2f((u16)(v & 0xffffu));
        a1 += bf2f((u16)(v >> 16));
    }
    float sc = 1.0f / (float)(c > 0 ? c : 1);
    unsigned int o = ((unsigned int)f2bf(a1 * sc) << 16) | (unsigned int)f2bf(a0 * sc);
    ((unsigned int*)Abuf)[(size_t)dst * 192 + r * 64 + lane] = o;
}

// ---------- weight transpose: f32 (512 x BN) k-major -> bf16 Wt (BN x 512) n-major ----------
template <int BN>
__global__ __launch_bounds__(256) void transpose_w(const float* __restrict__ Wrel,
                                                   const float* __restrict__ Wroot,
                                                   u16* __restrict__ Wt) {
    int idx = blockIdx.x * 256 + threadIdx.x;
    if (idx >= BN * 512) return;
    int n = idx >> 9;
    int k = idx & 511;
    float v = (k < 384) ? Wrel[(size_t)k * BN + n] : Wroot[(size_t)(k - 384) * BN + n];
    Wt[idx] = f2bf(v);
}

// ---------- fused GEMM: Out(M,BN) = [Alo(M,384) | Ahi(M,128)]_bf16 @ Wt^T + bias ----------
template <int BN, bool RELU, bool OUTF32>
__global__ __launch_bounds__(256) void gemm_fused(const u16* __restrict__ Alo,
                                                  const u16* __restrict__ Ahi,
                                                  const u16* __restrict__ Wt,
                                                  const float* __restrict__ bias,
                                                  void* __restrict__ OutV) {
    constexpr int M = N_NODES;
    constexpr int BM = 128, BK = 32, KTOT = 512, KLO = 384;
    __shared__ __align__(16) u16 As[BM * BK];
    __shared__ __align__(16) u16 Bs[BN * BK];
    const int t = threadIdx.x;
    const int w = t >> 6, l = t & 63;
    const int bm = blockIdx.x * BM;
    constexpr int WN  = (BN == 128) ? 2 : 1;
    constexpr int WTM = (BN == 128) ? 64 : 32;
    constexpr int WTN = 64;
    constexpr int MI = WTM / 16, NI = WTN / 16;
    const int wm = w / WN, wn = w % WN;
    const int q = l >> 4, lm = l & 15;   // quad, intra-16 index

    f32x4 acc[MI][NI] = {};

    const int ar = t >> 2;            // 0..63
    const int ac = (t & 3) * 8;       // 0,8,16,24

    for (int kt = 0; kt < KTOT / BK; ++kt) {
        const int k0 = kt * BK;
        const u16* base; int stride, kk;
        if (k0 < KLO) { base = Alo; stride = 384; kk = k0; }
        else          { base = Ahi; stride = 128; kk = k0 - KLO; }
        short8 va[2];
        #pragma unroll
        for (int i = 0; i < 2; ++i) {
            int gr = bm + i * 64 + ar; if (gr >= M) gr = M - 1;
            va[i] = *(const short8*)(base + (size_t)gr * stride + kk + ac);
        }
        short8 vb[BN / 64];
        #pragma unroll
        for (int i = 0; i < BN / 64; ++i) {
            int rn = i * 64 + ar;
            vb[i] = *(const short8*)(Wt + (size_t)rn * KTOT + k0 + ac);
        }
        __syncthreads();   // previous iteration done reading LDS
        #pragma unroll
        for (int i = 0; i < 2; ++i)
            *(short8*)&As[(i * 64 + ar) * BK + ac] = va[i];
        #pragma unroll
        for (int i = 0; i < BN / 64; ++i)
            *(short8*)&Bs[(i * 64 + ar) * BK + ac] = vb[i];
        __syncthreads();
        short8 fa[MI], fb[NI];
        #pragma unroll
        for (int mi = 0; mi < MI; ++mi)
            fa[mi] = *(const short8*)&As[(wm * WTM + mi * 16 + lm) * BK + q * 8];
        #pragma unroll
        for (int ni = 0; ni < NI; ++ni)
            fb[ni] = *(const short8*)&Bs[(wn * WTN + ni * 16 + lm) * BK + q * 8];
        #pragma unroll
        for (int mi = 0; mi < MI; ++mi)
            #pragma unroll
            for (int ni = 0; ni < NI; ++ni)
                acc[mi][ni] = __builtin_amdgcn_mfma_f32_16x16x32_bf16(
                    fa[mi], fb[ni], acc[mi][ni], 0, 0, 0);
    }
    // epilogue: C/D layout col=lane&15, row=q*4+reg
    #pragma unroll
    for (int mi = 0; mi < MI; ++mi) {
        #pragma unroll
        for (int ni = 0; ni < NI; ++ni) {
            int gc = wn * WTN + ni * 16 + lm;
            float bv = bias[gc];
            #pragma unroll
            for (int rg = 0; rg < 4; ++rg) {
                int gr = bm + wm * WTM + mi * 16 + q * 4 + rg;
                if (gr < M) {
                    float v = acc[mi][ni][rg] + bv;
                    if (RELU) v = fmaxf(v, 0.0f);
                    if (OUTF32) ((float*)OutV)[(size_t)gr * BN + gc] = v;
                    else        ((u16*)OutV)[(size_t)gr * BN + gc] = f2bf(v);
                }
            }
        }
    }
}

// ---------- final pair MLP: tanh(concat(node[nest],node[food]) @ fcW + fcb), all f32 ----------
__global__ __launch_bounds__(128) void pair_mlp(const float* __restrict__ node,
                                                const int* __restrict__ nest,
                                                const int* __restrict__ food,
                                                const float* __restrict__ fcW,
                                                const float* __restrict__ fcb,
                                                float* __restrict__ out) {
    int p = blockIdx.x;
    int t = threadIdx.x;
    __shared__ float pv[128];
    int n0 = nest[p], n1 = food[p];
    if ((unsigned)n0 >= (unsigned)N_NODES) n0 = 0;
    if ((unsigned)n1 >= (unsigned)N_NODES) n1 = 0;
    if (t < 64) pv[t] = node[(size_t)n0 * 64 + t];
    else        pv[t] = node[(size_t)n1 * 64 + (t - 64)];
    __syncthreads();
    float s = fcb[t];
    #pragma unroll 4
    for (int k = 0; k < 128; ++k)
        s += pv[k] * fcW[k * 128 + t];
    out[(size_t)p * 128 + t] = tanhf(s);
}

extern "C" void kernel_launch(void* const* d_in, const int* in_sizes, int n_in,
                              void* d_out, int out_size, void* d_ws, size_t ws_size,
                              hipStream_t stream) {
    const float* x    = (const float*)d_in[0];
    const int* esrc   = (const int*)d_in[1];
    const int* edst   = (const int*)d_in[2];
    const int* etyp   = (const int*)d_in[3];
    // d_in[4] edge_attr: dead code in reference
    const int* nest   = (const int*)d_in[5];
    const int* food   = (const int*)d_in[6];
    const float* Wrel1  = (const float*)d_in[7];
    const float* Wroot1 = (const float*)d_in[8];
    const float* b1     = (const float*)d_in[9];
    const float* Wrel2  = (const float*)d_in[10];
    const float* Wroot2 = (const float*)d_in[11];
    const float* b2     = (const float*)d_in[12];
    const float* fcW    = (const float*)d_in[13];
    const float* fcb    = (const float*)d_in[14];
    float* out = (float*)d_out;

    // workspace layout (256B aligned chunks)
    char* ws = (char*)d_ws;
    size_t off = 0;
    auto alloc_b = [&](size_t bytes) -> void* {
        void* p = ws + off;
        off += (bytes + 255) & ~(size_t)255;
        return p;
    };
    int* bc          = (int*)alloc_b((size_t)NBIN * NBLK * 4);
    int* sc          = (int*)alloc_b((size_t)NBIN * NBLK * 4);
    int* bt          = (int*)alloc_b((size_t)NBIN * 4);
    int* bb          = (int*)alloc_b((size_t)(NBIN + 1) * 4);
    unsigned int* bn = (unsigned int*)alloc_b((size_t)NEDGE * 4);
    int* seg_start   = (int*)alloc_b((size_t)NSEG * 4);
    int* cnt         = (int*)alloc_b((size_t)NSEG * 4);
    int* sorted_src  = (int*)alloc_b((size_t)NEDGE * 4);
    u16* Wt1         = (u16*)alloc_b((size_t)128 * 512 * 2);
    u16* Wt2         = (u16*)alloc_b((size_t)64 * 512 * 2);
    u16* xb          = (u16*)alloc_b((size_t)N_NODES * 128 * 2);   // bf16(x)
    u16* Abuf        = (u16*)alloc_b((size_t)N_NODES * 384 * 2);   // bf16 agg
    u16* h1          = (u16*)alloc_b((size_t)N_NODES * 128 * 2);   // bf16
    float* node      = (float*)alloc_b((size_t)N_NODES * 64 * 4);  // f32

    // CSR build: binned counting sort (no global atomics)
    p1_count<<<NBLK, 256, 0, stream>>>(edst, bc);
    p2a_binscan<<<NBIN, 512, 0, stream>>>(bc, sc, bt);
    p2b_totscan<<<1, 256, 0, stream>>>(bt, bb);
    p3_binscatter<<<NBLK, 256, 0, stream>>>(esrc, edst, etyp, sc, bb, bn);
    p4_finalize<<<NBIN, 256, 0, stream>>>(bn, bb, seg_start, cnt, sorted_src);

    // weight transposes (f32 -> bf16 n-major)
    transpose_w<128><<<(128 * 512) / 256, 256, 0, stream>>>(Wrel1, Wroot1, Wt1);
    transpose_w<64><<<(64 * 512) / 256, 256, 0, stream>>>(Wrel2, Wroot2, Wt2);

    // cast x -> bf16 (also the gather source for layer-1 aggregation)
    cast_kernel<<<(N_NODES * 128 / 4 + 255) / 256, 256, 0, stream>>>(x, xb, N_NODES * 128 / 4);

    const int segBlocks  = (NSEG * 64) / 256;            // 75000
    const int gemmBlocks = (N_NODES + 127) / 128;        // 782

    // layer 1: agg(xb) -> Abuf ; [Abuf|xb] @ Wt1 + b1, relu -> h1 (bf16)
    seg_mean<<<segBlocks, 256, 0, stream>>>((const unsigned int*)xb, seg_start, cnt, sorted_src, Abuf);
    gemm_fused<128, true, false><<<gemmBlocks, 256, 0, stream>>>(Abuf, xb, Wt1, b1, h1);

    // layer 2: agg(h1) -> Abuf ; [Abuf|h1] @ Wt2 + b2 -> node (f32)
    seg_mean<<<segBlocks, 256, 0, stream>>>((const unsigned int*)h1, seg_start, cnt, sorted_src, Abuf);
    gemm_fused<64, false, true><<<gemmBlocks, 256, 0, stream>>>(Abuf, h1, Wt2, b2, node);

    // pair MLP (f32)
    pair_mlp<<<NPAIR, 128, 0, stream>>>(node, nest, food, fcW, fcb, out);
}

// Round 8
// 486.187 us; speedup vs baseline: 1.3042x; 1.0031x over previous
//
#include <hip/hip_runtime.h>
#include <stdint.h>

typedef unsigned short u16;
typedef __attribute__((ext_vector_type(8))) short short8;
typedef __attribute__((ext_vector_type(4))) float f32x4;

#define N_NODES 100000
#define RREL    3
#define NEDGE   1600000
#define NPAIR   1024
#define NSEG    (RREL * N_NODES)

// binned CSR build params
#define EPB   4096
#define NBLK  ((NEDGE + EPB - 1) / EPB)   // 391
#define DPB   512                          // dsts per bin (dst >> 9)
#define NBIN  ((N_NODES + DPB - 1) / DPB)  // 196
#define LSEG  (DPB * RREL)                 // 1536 local segments per bin

// ---------- bf16 helpers ----------
__device__ __forceinline__ float bf2f(u16 h) {
    union { unsigned int u; float f; } c; c.u = ((unsigned int)h) << 16; return c.f;
}
__device__ __forceinline__ float bflo(unsigned int u) {
    union { unsigned int u; float f; } c; c.u = u << 16; return c.f;
}
__device__ __forceinline__ float bfhi(unsigned int u) {
    union { unsigned int u; float f; } c; c.u = u & 0xffff0000u; return c.f;
}
__device__ __forceinline__ u16 f2bf(float f) {
    union { float f; unsigned int u; } c; c.f = f;
    unsigned int u = c.u;
    u += 0x7fffu + ((u >> 16) & 1u);   // round-to-nearest-even
    return (u16)(u >> 16);
}

// ---------- cast f32 -> bf16, 4 elems/thread ----------
__global__ __launch_bounds__(256) void cast_kernel(const float* __restrict__ in,
                                                   u16* __restrict__ out, int n4) {
    int i = blockIdx.x * 256 + threadIdx.x;
    if (i >= n4) return;
    float4 v = ((const float4*)in)[i];
    uint2 o;
    o.x = ((unsigned int)f2bf(v.y) << 16) | (unsigned int)f2bf(v.x);
    o.y = ((unsigned int)f2bf(v.w) << 16) | (unsigned int)f2bf(v.z);
    ((uint2*)out)[i] = o;
}

// ========== CSR build: binned counting sort, no global atomics ==========

// P1: per-block histogram over dst-bins -> bc[bin * NBLK + blk]
__global__ __launch_bounds__(256) void p1_count(const int* __restrict__ ed,
                                                int* __restrict__ bc) {
    __shared__ int h[NBIN];
    int t = threadIdx.x, b = blockIdx.x;
    for (int i = t; i < NBIN; i += 256) h[i] = 0;
    __syncthreads();
    int e0 = b * EPB;
    int e1 = e0 + EPB; if (e1 > NEDGE) e1 = NEDGE;
    for (int i = e0 + t; i < e1; i += 256)
        atomicAdd(&h[ed[i] >> 9], 1);
    __syncthreads();
    for (int i = t; i < NBIN; i += 256) bc[i * NBLK + b] = h[i];
}

// P2a: per-bin scan of its 391 block-counts (one block per bin).
__global__ __launch_bounds__(512) void p2a_binscan(const int* __restrict__ bc,
                                                   int* __restrict__ sc,
                                                   int* __restrict__ bt) {
    __shared__ int wtot[8];
    int t = threadIdx.x, bin = blockIdx.x;
    int v = (t < NBLK) ? bc[bin * NBLK + t] : 0;
    int lane = t & 63, wv = t >> 6;
    int incl = v;
    #pragma unroll
    for (int d = 1; d < 64; d <<= 1) { int u = __shfl_up(incl, d); if (lane >= d) incl += u; }
    if (lane == 63) wtot[wv] = incl;
    __syncthreads();
    int wpre = 0;
    #pragma unroll
    for (int i = 0; i < 8; ++i) if (i < wv) wpre += wtot[i];
    if (t < NBLK) sc[bin * NBLK + t] = wpre + incl - v;
    if (t == 511) bt[bin] = wpre + incl;
}

// P2b: scan bin totals (196) -> bb[bin] global base; bb[NBIN] = NEDGE.
__global__ __launch_bounds__(256) void p2b_totscan(const int* __restrict__ bt,
                                                   int* __restrict__ bb) {
    __shared__ int wtot[4];
    int t = threadIdx.x;
    int v = (t < NBIN) ? bt[t] : 0;
    int lane = t & 63, wv = t >> 6;
    int incl = v;
    #pragma unroll
    for (int d = 1; d < 64; d <<= 1) { int u = __shfl_up(incl, d); if (lane >= d) incl += u; }
    if (lane == 63) wtot[wv] = incl;
    __syncthreads();
    int wpre = 0;
    #pragma unroll
    for (int i = 0; i < 4; ++i) if (i < wv) wpre += wtot[i];
    if (t < NBIN) bb[t] = wpre + incl - v;
    if (t == 0) bb[NBIN] = NEDGE;
}

// P3: write packed edges grouped by bin. packed = (src << 11) | (dstlow*3 + r)
__global__ __launch_bounds__(256) void p3_binscatter(const int* __restrict__ es,
                                                     const int* __restrict__ ed,
                                                     const int* __restrict__ et,
                                                     const int* __restrict__ sc,
                                                     const int* __restrict__ bb,
                                                     unsigned int* __restrict__ binned) {
    __shared__ int pos[NBIN];
    int t = threadIdx.x, b = blockIdx.x;
    for (int i = t; i < NBIN; i += 256) pos[i] = bb[i] + sc[i * NBLK + b];
    __syncthreads();
    int e0 = b * EPB;
    int e1 = e0 + EPB; if (e1 > NEDGE) e1 = NEDGE;
    for (int i = e0 + t; i < e1; i += 256) {
        int d = ed[i];
        int bin = d >> 9;
        unsigned int pk = ((unsigned int)es[i] << 11) | (unsigned int)((d & 511) * 3 + et[i]);
        int p = atomicAdd(&pos[bin], 1);
        binned[p] = pk;
    }
}

// P4: per-bin CSR finalize. seg = dst*3 + r (dst-major, dense in [0, 3N)).
__global__ __launch_bounds__(256) void p4_finalize(const unsigned int* __restrict__ binned,
                                                   const int* __restrict__ bb,
                                                   int* __restrict__ seg_start,
                                                   int* __restrict__ cnt,
                                                   int* __restrict__ sorted_src) {
    __shared__ int h[LSEG];
    __shared__ int cur[LSEG];
    __shared__ int wtot4[4];
    int t = threadIdx.x, bin = blockIdx.x;
    for (int i = t; i < LSEG; i += 256) h[i] = 0;
    __syncthreads();
    int eb = bb[bin];
    int ee = bb[bin + 1];
    for (int i = eb + t; i < ee; i += 256)
        atomicAdd(&h[binned[i] & 2047u], 1);
    __syncthreads();
    int i6 = t * 6;
    int s = 0;
    #pragma unroll
    for (int i = 0; i < 6; ++i) s += h[i6 + i];
    int lane = t & 63, wv = t >> 6;
    int incl = s;
    #pragma unroll
    for (int d = 1; d < 64; d <<= 1) { int v = __shfl_up(incl, d); if (lane >= d) incl += v; }
    if (lane == 63) wtot4[wv] = incl;
    __syncthreads();
    int wpre = 0;
    #pragma unroll
    for (int i = 0; i < 4; ++i) if (i < wv) wpre += wtot4[i];
    int run = wpre + incl - s;
    int segbase = bin * LSEG;
    #pragma unroll
    for (int i = 0; i < 6; ++i) {
        int ls = i6 + i;
        int c = h[ls];
        int seg = segbase + ls;
        if (seg < NSEG) { seg_start[seg] = eb + run; cnt[seg] = c; }
        cur[ls] = run;
        run += c;
    }
    __syncthreads();
    for (int i = eb + t; i < ee; i += 256) {
        unsigned int u = binned[i];
        int ls = (int)(u & 2047u);
        int p = atomicAdd(&cur[ls], 1);
        sorted_src[eb + p] = (int)(u >> 11);
    }
}

// ---------- per-segment mean; one wave per seg; quarter-wave row gather ----------
// Each 16-lane quarter loads one full 256B row (uint4/lane); wave does 4 edges/iter.
__global__ __launch_bounds__(256) void seg_mean(const uint4* __restrict__ X4,  // (N,16) uint4 = bf16x8
                                                const int* __restrict__ seg_start,
                                                const int* __restrict__ cnt,
                                                const int* __restrict__ sorted_src,
                                                u16* __restrict__ Abuf) {
    int wid  = (blockIdx.x * 256 + threadIdx.x) >> 6;
    int lane = threadIdx.x & 63;
    if (wid >= NSEG) return;
    int dst = wid / 3;
    int r   = wid - dst * 3;
    int c  = cnt[wid];
    int st = seg_start[wid];
    int q4 = lane >> 4, ql = lane & 15;

    float a0 = 0.f, a1 = 0.f, a2 = 0.f, a3 = 0.f,
          a4 = 0.f, a5 = 0.f, a6 = 0.f, a7 = 0.f;

    int nit = (c + 3) >> 2;
    for (int it = 0; it < nit; ++it) {
        int ei = it * 4 + q4;
        float w = (ei < c) ? 1.0f : 0.0f;
        int eic = (ei < c) ? ei : (c - 1);
        int src = sorted_src[st + eic];
        uint4 v = X4[(size_t)src * 16 + ql];
        a0 = fmaf(w, bflo(v.x), a0);
        a1 = fmaf(w, bfhi(v.x), a1);
        a2 = fmaf(w, bflo(v.y), a2);
        a3 = fmaf(w, bfhi(v.y), a3);
        a4 = fmaf(w, bflo(v.z), a4);
        a5 = fmaf(w, bfhi(v.z), a5);
        a6 = fmaf(w, bflo(v.w), a6);
        a7 = fmaf(w, bfhi(v.w), a7);
    }
    // fold quarters: lanes 0-15 accumulate quarters 1..3
    #pragma unroll
    for (int m = 16; m < 64; m <<= 1) {
        a0 += __shfl_xor(a0, m); a1 += __shfl_xor(a1, m);
        a2 += __shfl_xor(a2, m); a3 += __shfl_xor(a3, m);
        a4 += __shfl_xor(a4, m); a5 += __shfl_xor(a5, m);
        a6 += __shfl_xor(a6, m); a7 += __shfl_xor(a7, m);
    }
    if (lane < 16) {
        float sc = 1.0f / (float)(c > 0 ? c : 1);
        uint4 o;
        o.x = ((unsigned int)f2bf(a1 * sc) << 16) | (unsigned int)f2bf(a0 * sc);
        o.y = ((unsigned int)f2bf(a3 * sc) << 16) | (unsigned int)f2bf(a2 * sc);
        o.z = ((unsigned int)f2bf(a5 * sc) << 16) | (unsigned int)f2bf(a4 * sc);
        o.w = ((unsigned int)f2bf(a7 * sc) << 16) | (unsigned int)f2bf(a6 * sc);
        ((uint4*)Abuf)[(size_t)dst * 48 + r * 16 + ql] = o;
    }
}

// ---------- weight transpose: f32 (512 x BN) k-major -> bf16 Wt (BN x 512) n-major ----------
template <int BN>
__global__ __launch_bounds__(256) void transpose_w(const float* __restrict__ Wrel,
                                                   const float* __restrict__ Wroot,
                                                   u16* __restrict__ Wt) {
    int idx = blockIdx.x * 256 + threadIdx.x;
    if (idx >= BN * 512) return;
    int n = idx >> 9;
    int k = idx & 511;
    float v = (k < 384) ? Wrel[(size_t)k * BN + n] : Wroot[(size_t)(k - 384) * BN + n];
    Wt[idx] = f2bf(v);
}

// ---------- fused GEMM: Out(M,BN) = [Alo(M,384) | Ahi(M,128)]_bf16 @ Wt^T + bias ----------
template <int BN, bool RELU, bool OUTF32>
__global__ __launch_bounds__(256) void gemm_fused(const u16* __restrict__ Alo,
                                                  const u16* __restrict__ Ahi,
                                                  const u16* __restrict__ Wt,
                                                  const float* __restrict__ bias,
                                                  void* __restrict__ OutV) {
    constexpr int M = N_NODES;
    constexpr int BM = 128, BK = 32, KTOT = 512, KLO = 384;
    __shared__ __align__(16) u16 As[BM * BK];
    __shared__ __align__(16) u16 Bs[BN * BK];
    const int t = threadIdx.x;
    const int w = t >> 6, l = t & 63;
    const int bm = blockIdx.x * BM;
    constexpr int WN  = (BN == 128) ? 2 : 1;
    constexpr int WTM = (BN == 128) ? 64 : 32;
    constexpr int WTN = 64;
    constexpr int MI = WTM / 16, NI = WTN / 16;
    const int wm = w / WN, wn = w % WN;
    const int q = l >> 4, lm = l & 15;

    f32x4 acc[MI][NI] = {};

    const int ar = t >> 2;
    const int ac = (t & 3) * 8;

    for (int kt = 0; kt < KTOT / BK; ++kt) {
        const int k0 = kt * BK;
        const u16* base; int stride, kk;
        if (k0 < KLO) { base = Alo; stride = 384; kk = k0; }
        else          { base = Ahi; stride = 128; kk = k0 - KLO; }
        short8 va[2];
        #pragma unroll
        for (int i = 0; i < 2; ++i) {
            int gr = bm + i * 64 + ar; if (gr >= M) gr = M - 1;
            va[i] = *(const short8*)(base + (size_t)gr * stride + kk + ac);
        }
        short8 vb[BN / 64];
        #pragma unroll
        for (int i = 0; i < BN / 64; ++i) {
            int rn = i * 64 + ar;
            vb[i] = *(const short8*)(Wt + (size_t)rn * KTOT + k0 + ac);
        }
        __syncthreads();
        #pragma unroll
        for (int i = 0; i < 2; ++i)
            *(short8*)&As[(i * 64 + ar) * BK + ac] = va[i];
        #pragma unroll
        for (int i = 0; i < BN / 64; ++i)
            *(short8*)&Bs[(i * 64 + ar) * BK + ac] = vb[i];
        __syncthreads();
        short8 fa[MI], fb[NI];
        #pragma unroll
        for (int mi = 0; mi < MI; ++mi)
            fa[mi] = *(const short8*)&As[(wm * WTM + mi * 16 + lm) * BK + q * 8];
        #pragma unroll
        for (int ni = 0; ni < NI; ++ni)
            fb[ni] = *(const short8*)&Bs[(wn * WTN + ni * 16 + lm) * BK + q * 8];
        #pragma unroll
        for (int mi = 0; mi < MI; ++mi)
            #pragma unroll
            for (int ni = 0; ni < NI; ++ni)
                acc[mi][ni] = __builtin_amdgcn_mfma_f32_16x16x32_bf16(
                    fa[mi], fb[ni], acc[mi][ni], 0, 0, 0);
    }
    #pragma unroll
    for (int mi = 0; mi < MI; ++mi) {
        #pragma unroll
        for (int ni = 0; ni < NI; ++ni) {
            int gc = wn * WTN + ni * 16 + lm;
            float bv = bias[gc];
            #pragma unroll
            for (int rg = 0; rg < 4; ++rg) {
                int gr = bm + wm * WTM + mi * 16 + q * 4 + rg;
                if (gr < M) {
                    float v = acc[mi][ni][rg] + bv;
                    if (RELU) v = fmaxf(v, 0.0f);
                    if (OUTF32) ((float*)OutV)[(size_t)gr * BN + gc] = v;
                    else        ((u16*)OutV)[(size_t)gr * BN + gc] = f2bf(v);
                }
            }
        }
    }
}

// ---------- final pair MLP ----------
__global__ __launch_bounds__(128) void pair_mlp(const float* __restrict__ node,
                                                const int* __restrict__ nest,
                                                const int* __restrict__ food,
                                                const float* __restrict__ fcW,
                                                const float* __restrict__ fcb,
                                                float* __restrict__ out) {
    int p = blockIdx.x;
    int t = threadIdx.x;
    __shared__ float pv[128];
    int n0 = nest[p], n1 = food[p];
    if ((unsigned)n0 >= (unsigned)N_NODES) n0 = 0;
    if ((unsigned)n1 >= (unsigned)N_NODES) n1 = 0;
    if (t < 64) pv[t] = node[(size_t)n0 * 64 + t];
    else        pv[t] = node[(size_t)n1 * 64 + (t - 64)];
    __syncthreads();
    float s = fcb[t];
    #pragma unroll 4
    for (int k = 0; k < 128; ++k)
        s += pv[k] * fcW[k * 128 + t];
    out[(size_t)p * 128 + t] = tanhf(s);
}

extern "C" void kernel_launch(void* const* d_in, const int* in_sizes, int n_in,
                              void* d_out, int out_size, void* d_ws, size_t ws_size,
                              hipStream_t stream) {
    const float* x    = (const float*)d_in[0];
    const int* esrc   = (const int*)d_in[1];
    const int* edst   = (const int*)d_in[2];
    const int* etyp   = (const int*)d_in[3];
    const int* nest   = (const int*)d_in[5];
    const int* food   = (const int*)d_in[6];
    const float* Wrel1  = (const float*)d_in[7];
    const float* Wroot1 = (const float*)d_in[8];
    const float* b1     = (const float*)d_in[9];
    const float* Wrel2  = (const float*)d_in[10];
    const float* Wroot2 = (const float*)d_in[11];
    const float* b2     = (const float*)d_in[12];
    const float* fcW    = (const float*)d_in[13];
    const float* fcb    = (const float*)d_in[14];
    float* out = (float*)d_out;

    char* ws = (char*)d_ws;
    size_t off = 0;
    auto alloc_b = [&](size_t bytes) -> void* {
        void* p = ws + off;
        off += (bytes + 255) & ~(size_t)255;
        return p;
    };
    int* bc          = (int*)alloc_b((size_t)NBIN * NBLK * 4);
    int* sc          = (int*)alloc_b((size_t)NBIN * NBLK * 4);
    int* bt          = (int*)alloc_b((size_t)NBIN * 4);
    int* bb          = (int*)alloc_b((size_t)(NBIN + 1) * 4);
    unsigned int* bn = (unsigned int*)alloc_b((size_t)NEDGE * 4);
    int* seg_start   = (int*)alloc_b((size_t)NSEG * 4);
    int* cnt         = (int*)alloc_b((size_t)NSEG * 4);
    int* sorted_src  = (int*)alloc_b((size_t)NEDGE * 4);
    u16* Wt1         = (u16*)alloc_b((size_t)128 * 512 * 2);
    u16* Wt2         = (u16*)alloc_b((size_t)64 * 512 * 2);
    u16* xb          = (u16*)alloc_b((size_t)N_NODES * 128 * 2);
    u16* Abuf        = (u16*)alloc_b((size_t)N_NODES * 384 * 2);
    u16* h1          = (u16*)alloc_b((size_t)N_NODES * 128 * 2);
    float* node      = (float*)alloc_b((size_t)N_NODES * 64 * 4);

    // CSR build: binned counting sort (no global atomics)
    p1_count<<<NBLK, 256, 0, stream>>>(edst, bc);
    p2a_binscan<<<NBIN, 512, 0, stream>>>(bc, sc, bt);
    p2b_totscan<<<1, 256, 0, stream>>>(bt, bb);
    p3_binscatter<<<NBLK, 256, 0, stream>>>(esrc, edst, etyp, sc, bb, bn);
    p4_finalize<<<NBIN, 256, 0, stream>>>(bn, bb, seg_start, cnt, sorted_src);

    // weight transposes (f32 -> bf16 n-major)
    transpose_w<128><<<(128 * 512) / 256, 256, 0, stream>>>(Wrel1, Wroot1, Wt1);
    transpose_w<64><<<(64 * 512) / 256, 256, 0, stream>>>(Wrel2, Wroot2, Wt2);

    // cast x -> bf16 (gather source for layer-1 aggregation + GEMM A)
    cast_kernel<<<(N_NODES * 128 / 4 + 255) / 256, 256, 0, stream>>>(x, xb, N_NODES * 128 / 4);

    const int segBlocks  = (NSEG * 64) / 256;            // 75000
    const int gemmBlocks = (N_NODES + 127) / 128;        // 782

    // layer 1
    seg_mean<<<segBlocks, 256, 0, stream>>>((const uint4*)xb, seg_start, cnt, sorted_src, Abuf);
    gemm_fused<128, true, false><<<gemmBlocks, 256, 0, stream>>>(Abuf, xb, Wt1, b1, h1);

    // layer 2
    seg_mean<<<segBlocks, 256, 0, stream>>>((const uint4*)h1, seg_start, cnt, sorted_src, Abuf);
    gemm_fused<64, false, true><<<gemmBlocks, 256, 0, stream>>>(Abuf, h1, Wt2, b2, node);

    // pair MLP (f32)
    pair_mlp<<<NPAIR, 128, 0, stream>>>(node, nest, food, fcW, fcb, out);
}

// Round 9
// 471.155 us; speedup vs baseline: 1.3458x; 1.0319x over previous
//
#include <hip/hip_runtime.h>
#include <stdint.h>

typedef unsigned short u16;
typedef __attribute__((ext_vector_type(8))) short short8;
typedef __attribute__((ext_vector_type(4))) float f32x4;

#define N_NODES 100000
#define RREL    3
#define NEDGE   1600000
#define NPAIR   1024
#define NSEG    (RREL * N_NODES)

// binned CSR build params
#define EPB   4096
#define NBLK  ((NEDGE + EPB - 1) / EPB)   // 391
#define DPB   512                          // dsts per bin (dst >> 9)
#define NBIN  ((N_NODES + DPB - 1) / DPB)  // 196
#define LSEG  (DPB * RREL)                 // 1536 local segments per bin

// ---------- bf16 helpers ----------
__device__ __forceinline__ float bf2f(u16 h) {
    union { unsigned int u; float f; } c; c.u = ((unsigned int)h) << 16; return c.f;
}
__device__ __forceinline__ float bflo(unsigned int u) {
    union { unsigned int u; float f; } c; c.u = u << 16; return c.f;
}
__device__ __forceinline__ float bfhi(unsigned int u) {
    union { unsigned int u; float f; } c; c.u = u & 0xffff0000u; return c.f;
}
__device__ __forceinline__ u16 f2bf(float f) {
    union { float f; unsigned int u; } c; c.f = f;
    unsigned int u = c.u;
    u += 0x7fffu + ((u >> 16) & 1u);   // round-to-nearest-even
    return (u16)(u >> 16);
}

// ---------- cast f32 -> bf16, 4 elems/thread ----------
__global__ __launch_bounds__(256) void cast_kernel(const float* __restrict__ in,
                                                   u16* __restrict__ out, int n4) {
    int i = blockIdx.x * 256 + threadIdx.x;
    if (i >= n4) return;
    float4 v = ((const float4*)in)[i];
    uint2 o;
    o.x = ((unsigned int)f2bf(v.y) << 16) | (unsigned int)f2bf(v.x);
    o.y = ((unsigned int)f2bf(v.w) << 16) | (unsigned int)f2bf(v.z);
    ((uint2*)out)[i] = o;
}

// ========== CSR build: binned counting sort, no global atomics ==========

__global__ __launch_bounds__(256) void p1_count(const int* __restrict__ ed,
                                                int* __restrict__ bc) {
    __shared__ int h[NBIN];
    int t = threadIdx.x, b = blockIdx.x;
    for (int i = t; i < NBIN; i += 256) h[i] = 0;
    __syncthreads();
    int e0 = b * EPB;
    int e1 = e0 + EPB; if (e1 > NEDGE) e1 = NEDGE;
    for (int i = e0 + t; i < e1; i += 256)
        atomicAdd(&h[ed[i] >> 9], 1);
    __syncthreads();
    for (int i = t; i < NBIN; i += 256) bc[i * NBLK + b] = h[i];
}

__global__ __launch_bounds__(512) void p2a_binscan(const int* __restrict__ bc,
                                                   int* __restrict__ sc,
                                                   int* __restrict__ bt) {
    __shared__ int wtot[8];
    int t = threadIdx.x, bin = blockIdx.x;
    int v = (t < NBLK) ? bc[bin * NBLK + t] : 0;
    int lane = t & 63, wv = t >> 6;
    int incl = v;
    #pragma unroll
    for (int d = 1; d < 64; d <<= 1) { int u = __shfl_up(incl, d); if (lane >= d) incl += u; }
    if (lane == 63) wtot[wv] = incl;
    __syncthreads();
    int wpre = 0;
    #pragma unroll
    for (int i = 0; i < 8; ++i) if (i < wv) wpre += wtot[i];
    if (t < NBLK) sc[bin * NBLK + t] = wpre + incl - v;
    if (t == 511) bt[bin] = wpre + incl;
}

__global__ __launch_bounds__(256) void p2b_totscan(const int* __restrict__ bt,
                                                   int* __restrict__ bb) {
    __shared__ int wtot[4];
    int t = threadIdx.x;
    int v = (t < NBIN) ? bt[t] : 0;
    int lane = t & 63, wv = t >> 6;
    int incl = v;
    #pragma unroll
    for (int d = 1; d < 64; d <<= 1) { int u = __shfl_up(incl, d); if (lane >= d) incl += u; }
    if (lane == 63) wtot[wv] = incl;
    __syncthreads();
    int wpre = 0;
    #pragma unroll
    for (int i = 0; i < 4; ++i) if (i < wv) wpre += wtot[i];
    if (t < NBIN) bb[t] = wpre + incl - v;
    if (t == 0) bb[NBIN] = NEDGE;
}

__global__ __launch_bounds__(256) void p3_binscatter(const int* __restrict__ es,
                                                     const int* __restrict__ ed,
                                                     const int* __restrict__ et,
                                                     const int* __restrict__ sc,
                                                     const int* __restrict__ bb,
                                                     unsigned int* __restrict__ binned) {
    __shared__ int pos[NBIN];
    int t = threadIdx.x, b = blockIdx.x;
    for (int i = t; i < NBIN; i += 256) pos[i] = bb[i] + sc[i * NBLK + b];
    __syncthreads();
    int e0 = b * EPB;
    int e1 = e0 + EPB; if (e1 > NEDGE) e1 = NEDGE;
    for (int i = e0 + t; i < e1; i += 256) {
        int d = ed[i];
        int bin = d >> 9;
        unsigned int pk = ((unsigned int)es[i] << 11) | (unsigned int)((d & 511) * 3 + et[i]);
        int p = atomicAdd(&pos[bin], 1);
        binned[p] = pk;
    }
}

__global__ __launch_bounds__(256) void p4_finalize(const unsigned int* __restrict__ binned,
                                                   const int* __restrict__ bb,
                                                   int* __restrict__ seg_start,
                                                   int* __restrict__ cnt,
                                                   int* __restrict__ sorted_src) {
    __shared__ int h[LSEG];
    __shared__ int cur[LSEG];
    __shared__ int wtot4[4];
    int t = threadIdx.x, bin = blockIdx.x;
    for (int i = t; i < LSEG; i += 256) h[i] = 0;
    __syncthreads();
    int eb = bb[bin];
    int ee = bb[bin + 1];
    for (int i = eb + t; i < ee; i += 256)
        atomicAdd(&h[binned[i] & 2047u], 1);
    __syncthreads();
    int i6 = t * 6;
    int s = 0;
    #pragma unroll
    for (int i = 0; i < 6; ++i) s += h[i6 + i];
    int lane = t & 63, wv = t >> 6;
    int incl = s;
    #pragma unroll
    for (int d = 1; d < 64; d <<= 1) { int v = __shfl_up(incl, d); if (lane >= d) incl += v; }
    if (lane == 63) wtot4[wv] = incl;
    __syncthreads();
    int wpre = 0;
    #pragma unroll
    for (int i = 0; i < 4; ++i) if (i < wv) wpre += wtot4[i];
    int run = wpre + incl - s;
    int segbase = bin * LSEG;
    #pragma unroll
    for (int i = 0; i < 6; ++i) {
        int ls = i6 + i;
        int c = h[ls];
        int seg = segbase + ls;
        if (seg < NSEG) { seg_start[seg] = eb + run; cnt[seg] = c; }
        cur[ls] = run;
        run += c;
    }
    __syncthreads();
    for (int i = eb + t; i < ee; i += 256) {
        unsigned int u = binned[i];
        int ls = (int)(u & 2047u);
        int p = atomicAdd(&cur[ls], 1);
        sorted_src[eb + p] = (int)(u >> 11);
    }
}

// ---------- per-segment mean; one wave per seg; 16 edges/iter, 4 chains in flight ----------
__global__ __launch_bounds__(256) void seg_mean(const uint4* __restrict__ X4,  // (N,16) uint4 = bf16x8
                                                const int* __restrict__ seg_start,
                                                const int* __restrict__ cnt,
                                                const int* __restrict__ sorted_src,
                                                u16* __restrict__ Abuf) {
    int wid  = (blockIdx.x * 256 + threadIdx.x) >> 6;
    int lane = threadIdx.x & 63;
    if (wid >= NSEG) return;
    int dst = wid / 3;
    int r   = wid - dst * 3;
    int c  = cnt[wid];
    int st = seg_start[wid];
    int q4 = lane >> 4, ql = lane & 15;

    float a0 = 0.f, a1 = 0.f, a2 = 0.f, a3 = 0.f,
          a4 = 0.f, a5 = 0.f, a6 = 0.f, a7 = 0.f;

    // iteration covers 16 edges; this quarter handles edges base+q4*4 .. +3
    for (int base = 0; base < c; base += 16) {
        int i0 = base + q4 * 4;
        int e0 = i0, e1 = i0 + 1, e2 = i0 + 2, e3 = i0 + 3;
        float w0 = (e0 < c) ? 1.f : 0.f;
        float w1 = (e1 < c) ? 1.f : 0.f;
        float w2 = (e2 < c) ? 1.f : 0.f;
        float w3 = (e3 < c) ? 1.f : 0.f;
        int c0 = (e0 < c) ? e0 : (c - 1);
        int c1 = (e1 < c) ? e1 : (c - 1);
        int c2 = (e2 < c) ? e2 : (c - 1);
        int c3 = (e3 < c) ? e3 : (c - 1);
        // 4 independent index loads
        int s0 = sorted_src[st + c0];
        int s1 = sorted_src[st + c1];
        int s2 = sorted_src[st + c2];
        int s3 = sorted_src[st + c3];
        // 4 independent row loads (4 KB in flight per wave)
        uint4 v0 = X4[(size_t)s0 * 16 + ql];
        uint4 v1 = X4[(size_t)s1 * 16 + ql];
        uint4 v2 = X4[(size_t)s2 * 16 + ql];
        uint4 v3 = X4[(size_t)s3 * 16 + ql];
        a0 = fmaf(w0, bflo(v0.x), a0); a1 = fmaf(w0, bfhi(v0.x), a1);
        a2 = fmaf(w0, bflo(v0.y), a2); a3 = fmaf(w0, bfhi(v0.y), a3);
        a4 = fmaf(w0, bflo(v0.z), a4); a5 = fmaf(w0, bfhi(v0.z), a5);
        a6 = fmaf(w0, bflo(v0.w), a6); a7 = fmaf(w0, bfhi(v0.w), a7);
        a0 = fmaf(w1, bflo(v1.x), a0); a1 = fmaf(w1, bfhi(v1.x), a1);
        a2 = fmaf(w1, bflo(v1.y), a2); a3 = fmaf(w1, bfhi(v1.y), a3);
        a4 = fmaf(w1, bflo(v1.z), a4); a5 = fmaf(w1, bfhi(v1.z), a5);
        a6 = fmaf(w1, bflo(v1.w), a6); a7 = fmaf(w1, bfhi(v1.w), a7);
        a0 = fmaf(w2, bflo(v2.x), a0); a1 = fmaf(w2, bfhi(v2.x), a1);
        a2 = fmaf(w2, bflo(v2.y), a2); a3 = fmaf(w2, bfhi(v2.y), a3);
        a4 = fmaf(w2, bflo(v2.z), a4); a5 = fmaf(w2, bfhi(v2.z), a5);
        a6 = fmaf(w2, bflo(v2.w), a6); a7 = fmaf(w2, bfhi(v2.w), a7);
        a0 = fmaf(w3, bflo(v3.x), a0); a1 = fmaf(w3, bfhi(v3.x), a1);
        a2 = fmaf(w3, bflo(v3.y), a2); a3 = fmaf(w3, bfhi(v3.y), a3);
        a4 = fmaf(w3, bflo(v3.z), a4); a5 = fmaf(w3, bfhi(v3.z), a5);
        a6 = fmaf(w3, bflo(v3.w), a6); a7 = fmaf(w3, bfhi(v3.w), a7);
    }
    // fold quarters
    #pragma unroll
    for (int m = 16; m < 64; m <<= 1) {
        a0 += __shfl_xor(a0, m); a1 += __shfl_xor(a1, m);
        a2 += __shfl_xor(a2, m); a3 += __shfl_xor(a3, m);
        a4 += __shfl_xor(a4, m); a5 += __shfl_xor(a5, m);
        a6 += __shfl_xor(a6, m); a7 += __shfl_xor(a7, m);
    }
    if (lane < 16) {
        float sc = 1.0f / (float)(c > 0 ? c : 1);
        uint4 o;
        o.x = ((unsigned int)f2bf(a1 * sc) << 16) | (unsigned int)f2bf(a0 * sc);
        o.y = ((unsigned int)f2bf(a3 * sc) << 16) | (unsigned int)f2bf(a2 * sc);
        o.z = ((unsigned int)f2bf(a5 * sc) << 16) | (unsigned int)f2bf(a4 * sc);
        o.w = ((unsigned int)f2bf(a7 * sc) << 16) | (unsigned int)f2bf(a6 * sc);
        ((uint4*)Abuf)[(size_t)dst * 48 + r * 16 + ql] = o;
    }
}

// ---------- weight transpose ----------
template <int BN>
__global__ __launch_bounds__(256) void transpose_w(const float* __restrict__ Wrel,
                                                   const float* __restrict__ Wroot,
                                                   u16* __restrict__ Wt) {
    int idx = blockIdx.x * 256 + threadIdx.x;
    if (idx >= BN * 512) return;
    int n = idx >> 9;
    int k = idx & 511;
    float v = (k < 384) ? Wrel[(size_t)k * BN + n] : Wroot[(size_t)(k - 384) * BN + n];
    Wt[idx] = f2bf(v);
}

// ---------- fused GEMM ----------
template <int BN, bool RELU, bool OUTF32>
__global__ __launch_bounds__(256) void gemm_fused(const u16* __restrict__ Alo,
                                                  const u16* __restrict__ Ahi,
                                                  const u16* __restrict__ Wt,
                                                  const float* __restrict__ bias,
                                                  void* __restrict__ OutV) {
    constexpr int M = N_NODES;
    constexpr int BM = 128, BK = 32, KTOT = 512, KLO = 384;
    __shared__ __align__(16) u16 As[BM * BK];
    __shared__ __align__(16) u16 Bs[BN * BK];
    const int t = threadIdx.x;
    const int w = t >> 6, l = t & 63;
    const int bm = blockIdx.x * BM;
    constexpr int WN  = (BN == 128) ? 2 : 1;
    constexpr int WTM = (BN == 128) ? 64 : 32;
    constexpr int WTN = 64;
    constexpr int MI = WTM / 16, NI = WTN / 16;
    const int wm = w / WN, wn = w % WN;
    const int q = l >> 4, lm = l & 15;

    f32x4 acc[MI][NI] = {};

    const int ar = t >> 2;
    const int ac = (t & 3) * 8;

    for (int kt = 0; kt < KTOT / BK; ++kt) {
        const int k0 = kt * BK;
        const u16* base; int stride, kk;
        if (k0 < KLO) { base = Alo; stride = 384; kk = k0; }
        else          { base = Ahi; stride = 128; kk = k0 - KLO; }
        short8 va[2];
        #pragma unroll
        for (int i = 0; i < 2; ++i) {
            int gr = bm + i * 64 + ar; if (gr >= M) gr = M - 1;
            va[i] = *(const short8*)(base + (size_t)gr * stride + kk + ac);
        }
        short8 vb[BN / 64];
        #pragma unroll
        for (int i = 0; i < BN / 64; ++i) {
            int rn = i * 64 + ar;
            vb[i] = *(const short8*)(Wt + (size_t)rn * KTOT + k0 + ac);
        }
        __syncthreads();
        #pragma unroll
        for (int i = 0; i < 2; ++i)
            *(short8*)&As[(i * 64 + ar) * BK + ac] = va[i];
        #pragma unroll
        for (int i = 0; i < BN / 64; ++i)
            *(short8*)&Bs[(i * 64 + ar) * BK + ac] = vb[i];
        __syncthreads();
        short8 fa[MI], fb[NI];
        #pragma unroll
        for (int mi = 0; mi < MI; ++mi)
            fa[mi] = *(const short8*)&As[(wm * WTM + mi * 16 + lm) * BK + q * 8];
        #pragma unroll
        for (int ni = 0; ni < NI; ++ni)
            fb[ni] = *(const short8*)&Bs[(wn * WTN + ni * 16 + lm) * BK + q * 8];
        #pragma unroll
        for (int mi = 0; mi < MI; ++mi)
            #pragma unroll
            for (int ni = 0; ni < NI; ++ni)
                acc[mi][ni] = __builtin_amdgcn_mfma_f32_16x16x32_bf16(
                    fa[mi], fb[ni], acc[mi][ni], 0, 0, 0);
    }
    #pragma unroll
    for (int mi = 0; mi < MI; ++mi) {
        #pragma unroll
        for (int ni = 0; ni < NI; ++ni) {
            int gc = wn * WTN + ni * 16 + lm;
            float bv = bias[gc];
            #pragma unroll
            for (int rg = 0; rg < 4; ++rg) {
                int gr = bm + wm * WTM + mi * 16 + q * 4 + rg;
                if (gr < M) {
                    float v = acc[mi][ni][rg] + bv;
                    if (RELU) v = fmaxf(v, 0.0f);
                    if (OUTF32) ((float*)OutV)[(size_t)gr * BN + gc] = v;
                    else        ((u16*)OutV)[(size_t)gr * BN + gc] = f2bf(v);
                }
            }
        }
    }
}

// ---------- final pair MLP ----------
__global__ __launch_bounds__(128) void pair_mlp(const float* __restrict__ node,
                                                const int* __restrict__ nest,
                                                const int* __restrict__ food,
                                                const float* __restrict__ fcW,
                                                const float* __restrict__ fcb,
                                                float* __restrict__ out) {
    int p = blockIdx.x;
    int t = threadIdx.x;
    __shared__ float pv[128];
    int n0 = nest[p], n1 = food[p];
    if ((unsigned)n0 >= (unsigned)N_NODES) n0 = 0;
    if ((unsigned)n1 >= (unsigned)N_NODES) n1 = 0;
    if (t < 64) pv[t] = node[(size_t)n0 * 64 + t];
    else        pv[t] = node[(size_t)n1 * 64 + (t - 64)];
    __syncthreads();
    float s = fcb[t];
    #pragma unroll 4
    for (int k = 0; k < 128; ++k)
        s += pv[k] * fcW[k * 128 + t];
    out[(size_t)p * 128 + t] = tanhf(s);
}

extern "C" void kernel_launch(void* const* d_in, const int* in_sizes, int n_in,
                              void* d_out, int out_size, void* d_ws, size_t ws_size,
                              hipStream_t stream) {
    const float* x    = (const float*)d_in[0];
    const int* esrc   = (const int*)d_in[1];
    const int* edst   = (const int*)d_in[2];
    const int* etyp   = (const int*)d_in[3];
    const int* nest   = (const int*)d_in[5];
    const int* food   = (const int*)d_in[6];
    const float* Wrel1  = (const float*)d_in[7];
    const float* Wroot1 = (const float*)d_in[8];
    const float* b1     = (const float*)d_in[9];
    const float* Wrel2  = (const float*)d_in[10];
    const float* Wroot2 = (const float*)d_in[11];
    const float* b2     = (const float*)d_in[12];
    const float* fcW    = (const float*)d_in[13];
    const float* fcb    = (const float*)d_in[14];
    float* out = (float*)d_out;

    char* ws = (char*)d_ws;
    size_t off = 0;
    auto alloc_b = [&](size_t bytes) -> void* {
        void* p = ws + off;
        off += (bytes + 255) & ~(size_t)255;
        return p;
    };
    int* bc          = (int*)alloc_b((size_t)NBIN * NBLK * 4);
    int* sc          = (int*)alloc_b((size_t)NBIN * NBLK * 4);
    int* bt          = (int*)alloc_b((size_t)NBIN * 4);
    int* bb          = (int*)alloc_b((size_t)(NBIN + 1) * 4);
    unsigned int* bn = (unsigned int*)alloc_b((size_t)NEDGE * 4);
    int* seg_start   = (int*)alloc_b((size_t)NSEG * 4);
    int* cnt         = (int*)alloc_b((size_t)NSEG * 4);
    int* sorted_src  = (int*)alloc_b((size_t)NEDGE * 4);
    u16* Wt1         = (u16*)alloc_b((size_t)128 * 512 * 2);
    u16* Wt2         = (u16*)alloc_b((size_t)64 * 512 * 2);
    u16* xb          = (u16*)alloc_b((size_t)N_NODES * 128 * 2);
    u16* Abuf        = (u16*)alloc_b((size_t)N_NODES * 384 * 2);
    u16* h1          = (u16*)alloc_b((size_t)N_NODES * 128 * 2);
    float* node      = (float*)alloc_b((size_t)N_NODES * 64 * 4);

    // CSR build: binned counting sort (no global atomics)
    p1_count<<<NBLK, 256, 0, stream>>>(edst, bc);
    p2a_binscan<<<NBIN, 512, 0, stream>>>(bc, sc, bt);
    p2b_totscan<<<1, 256, 0, stream>>>(bt, bb);
    p3_binscatter<<<NBLK, 256, 0, stream>>>(esrc, edst, etyp, sc, bb, bn);
    p4_finalize<<<NBIN, 256, 0, stream>>>(bn, bb, seg_start, cnt, sorted_src);

    // weight transposes (f32 -> bf16 n-major)
    transpose_w<128><<<(128 * 512) / 256, 256, 0, stream>>>(Wrel1, Wroot1, Wt1);
    transpose_w<64><<<(64 * 512) / 256, 256, 0, stream>>>(Wrel2, Wroot2, Wt2);

    // cast x -> bf16 (gather source for layer-1 aggregation + GEMM A)
    cast_kernel<<<(N_NODES * 128 / 4 + 255) / 256, 256, 0, stream>>>(x, xb, N_NODES * 128 / 4);

    const int segBlocks  = (NSEG * 64) / 256;            // 75000
    const int gemmBlocks = (N_NODES + 127) / 128;        // 782

    // layer 1
    seg_mean<<<segBlocks, 256, 0, stream>>>((const uint4*)xb, seg_start, cnt, sorted_src, Abuf);
    gemm_fused<128, true, false><<<gemmBlocks, 256, 0, stream>>>(Abuf, xb, Wt1, b1, h1);

    // layer 2
    seg_mean<<<segBlocks, 256, 0, stream>>>((const uint4*)h1, seg_start, cnt, sorted_src, Abuf);
    gemm_fused<64, false, true><<<gemmBlocks, 256, 0, stream>>>(Abuf, h1, Wt2, b2, node);

    // pair MLP (f32)
    pair_mlp<<<NPAIR, 128, 0, stream>>>(node, nest, food, fcW, fcb, out);
}

// Round 10
// 397.874 us; speedup vs baseline: 1.5936x; 1.1842x over previous
//
#include <hip/hip_runtime.h>
#include <stdint.h>

typedef unsigned short u16;
typedef __attribute__((ext_vector_type(8))) short short8;
typedef __attribute__((ext_vector_type(4))) float f32x4;

#define N_NODES 100000
#define RREL    3
#define NEDGE   1600000
#define NPAIR   1024
#define NSEG    (RREL * N_NODES)

// binned CSR build params
#define EPB   4096
#define NBLK  ((NEDGE + EPB - 1) / EPB)   // 391
#define DPB   512                          // dsts per bin (dst >> 9)
#define NBIN  ((N_NODES + DPB - 1) / DPB)  // 196
#define LSEG  (DPB * RREL)                 // 1536 local segments per bin

// ---------- bf16 helpers ----------
__device__ __forceinline__ float bflo(unsigned int u) {
    union { unsigned int u; float f; } c; c.u = u << 16; return c.f;
}
__device__ __forceinline__ float bfhi(unsigned int u) {
    union { unsigned int u; float f; } c; c.u = u & 0xffff0000u; return c.f;
}
__device__ __forceinline__ u16 f2bf(float f) {
    union { float f; unsigned int u; } c; c.f = f;
    unsigned int u = c.u;
    u += 0x7fffu + ((u >> 16) & 1u);   // round-to-nearest-even
    return (u16)(u >> 16);
}

// ---------- cast f32 -> bf16, 4 elems/thread ----------
__global__ __launch_bounds__(256) void cast_kernel(const float* __restrict__ in,
                                                   u16* __restrict__ out, int n4) {
    int i = blockIdx.x * 256 + threadIdx.x;
    if (i >= n4) return;
    float4 v = ((const float4*)in)[i];
    uint2 o;
    o.x = ((unsigned int)f2bf(v.y) << 16) | (unsigned int)f2bf(v.x);
    o.y = ((unsigned int)f2bf(v.w) << 16) | (unsigned int)f2bf(v.z);
    ((uint2*)out)[i] = o;
}

// ========== CSR build: binned counting sort, no global atomics ==========

__global__ __launch_bounds__(256) void p1_count(const int* __restrict__ ed,
                                                int* __restrict__ bc) {
    __shared__ int h[NBIN];
    int t = threadIdx.x, b = blockIdx.x;
    for (int i = t; i < NBIN; i += 256) h[i] = 0;
    __syncthreads();
    int e0 = b * EPB;
    int e1 = e0 + EPB; if (e1 > NEDGE) e1 = NEDGE;
    for (int i = e0 + t; i < e1; i += 256)
        atomicAdd(&h[ed[i] >> 9], 1);
    __syncthreads();
    for (int i = t; i < NBIN; i += 256) bc[i * NBLK + b] = h[i];
}

__global__ __launch_bounds__(512) void p2a_binscan(const int* __restrict__ bc,
                                                   int* __restrict__ sc,
                                                   int* __restrict__ bt) {
    __shared__ int wtot[8];
    int t = threadIdx.x, bin = blockIdx.x;
    int v = (t < NBLK) ? bc[bin * NBLK + t] : 0;
    int lane = t & 63, wv = t >> 6;
    int incl = v;
    #pragma unroll
    for (int d = 1; d < 64; d <<= 1) { int u = __shfl_up(incl, d); if (lane >= d) incl += u; }
    if (lane == 63) wtot[wv] = incl;
    __syncthreads();
    int wpre = 0;
    #pragma unroll
    for (int i = 0; i < 8; ++i) if (i < wv) wpre += wtot[i];
    if (t < NBLK) sc[bin * NBLK + t] = wpre + incl - v;
    if (t == 511) bt[bin] = wpre + incl;
}

__global__ __launch_bounds__(256) void p2b_totscan(const int* __restrict__ bt,
                                                   int* __restrict__ bb) {
    __shared__ int wtot[4];
    int t = threadIdx.x;
    int v = (t < NBIN) ? bt[t] : 0;
    int lane = t & 63, wv = t >> 6;
    int incl = v;
    #pragma unroll
    for (int d = 1; d < 64; d <<= 1) { int u = __shfl_up(incl, d); if (lane >= d) incl += u; }
    if (lane == 63) wtot[wv] = incl;
    __syncthreads();
    int wpre = 0;
    #pragma unroll
    for (int i = 0; i < 4; ++i) if (i < wv) wpre += wtot[i];
    if (t < NBIN) bb[t] = wpre + incl - v;
    if (t == 0) bb[NBIN] = NEDGE;
}

__global__ __launch_bounds__(256) void p3_binscatter(const int* __restrict__ es,
                                                     const int* __restrict__ ed,
                                                     const int* __restrict__ et,
                                                     const int* __restrict__ sc,
                                                     const int* __restrict__ bb,
                                                     unsigned int* __restrict__ binned) {
    __shared__ int pos[NBIN];
    int t = threadIdx.x, b = blockIdx.x;
    for (int i = t; i < NBIN; i += 256) pos[i] = bb[i] + sc[i * NBLK + b];
    __syncthreads();
    int e0 = b * EPB;
    int e1 = e0 + EPB; if (e1 > NEDGE) e1 = NEDGE;
    for (int i = e0 + t; i < e1; i += 256) {
        int d = ed[i];
        int bin = d >> 9;
        unsigned int pk = ((unsigned int)es[i] << 11) | (unsigned int)((d & 511) * 3 + et[i]);
        int p = atomicAdd(&pos[bin], 1);
        binned[p] = pk;
    }
}

__global__ __launch_bounds__(256) void p4_finalize(const unsigned int* __restrict__ binned,
                                                   const int* __restrict__ bb,
                                                   int* __restrict__ seg_start,
                                                   int* __restrict__ cnt,
                                                   int* __restrict__ sorted_src) {
    __shared__ int h[LSEG];
    __shared__ int cur[LSEG];
    __shared__ int wtot4[4];
    int t = threadIdx.x, bin = blockIdx.x;
    for (int i = t; i < LSEG; i += 256) h[i] = 0;
    __syncthreads();
    int eb = bb[bin];
    int ee = bb[bin + 1];
    for (int i = eb + t; i < ee; i += 256)
        atomicAdd(&h[binned[i] & 2047u], 1);
    __syncthreads();
    int i6 = t * 6;
    int s = 0;
    #pragma unroll
    for (int i = 0; i < 6; ++i) s += h[i6 + i];
    int lane = t & 63, wv = t >> 6;
    int incl = s;
    #pragma unroll
    for (int d = 1; d < 64; d <<= 1) { int v = __shfl_up(incl, d); if (lane >= d) incl += v; }
    if (lane == 63) wtot4[wv] = incl;
    __syncthreads();
    int wpre = 0;
    #pragma unroll
    for (int i = 0; i < 4; ++i) if (i < wv) wpre += wtot4[i];
    int run = wpre + incl - s;
    int segbase = bin * LSEG;
    #pragma unroll
    for (int i = 0; i < 6; ++i) {
        int ls = i6 + i;
        int c = h[ls];
        int seg = segbase + ls;
        if (seg < NSEG) { seg_start[seg] = eb + run; cnt[seg] = c; }
        cur[ls] = run;
        run += c;
    }
    __syncthreads();
    for (int i = eb + t; i < ee; i += 256) {
        unsigned int u = binned[i];
        int ls = (int)(u & 2047u);
        int p = atomicAdd(&cur[ls], 1);
        sorted_src[eb + p] = (int)(u >> 11);
    }
}

// ---------- per-segment mean; one QUARTER-WAVE per segment (wave = 4 segs) ----------
// lane ql holds features [ql*8, ql*8+8) of the row; no cross-lane fold needed.
// Indices batch-loaded 16 at a time and distributed via __shfl within the quarter.
__global__ __launch_bounds__(256) void seg_mean(const uint4* __restrict__ X4,  // (N,16) uint4 = bf16x8
                                                const int* __restrict__ seg_start,
                                                const int* __restrict__ cnt,
                                                const int* __restrict__ sorted_src,
                                                u16* __restrict__ Abuf) {
    int lane = threadIdx.x & 63;
    int q4 = lane >> 4, ql = lane & 15;
    int wid = ((blockIdx.x * 256 + threadIdx.x) >> 6) * 4 + q4;   // NSEG % 4 == 0
    if (wid >= NSEG) return;
    int c  = cnt[wid];
    int st = seg_start[wid];

    float a0 = 0.f, a1 = 0.f, a2 = 0.f, a3 = 0.f,
          a4 = 0.f, a5 = 0.f, a6 = 0.f, a7 = 0.f;

    int shbase = q4 * 16;
    for (int base = 0; base < c; base += 16) {
        int rem = c - base;                       // >= 1
        int ii  = (ql < rem) ? ql : (rem - 1);
        int idxv = sorted_src[st + base + ii];    // idx for edge base+ql (clamped)
        int lim = (rem < 16) ? rem : 16;
        for (int j = 0; j < lim; j += 4) {
            int e1 = j + 1, e2 = j + 2, e3 = j + 3;
            float w1 = (e1 < lim) ? 1.f : 0.f;
            float w2 = (e2 < lim) ? 1.f : 0.f;
            float w3 = (e3 < lim) ? 1.f : 0.f;
            int s0 = __shfl(idxv, shbase + j);
            int s1 = __shfl(idxv, shbase + ((e1 < lim) ? e1 : 0));
            int s2 = __shfl(idxv, shbase + ((e2 < lim) ? e2 : 0));
            int s3 = __shfl(idxv, shbase + ((e3 < lim) ? e3 : 0));
            // 4 independent row loads (16 rows / 4 KB in flight per wave)
            uint4 v0 = X4[(size_t)s0 * 16 + ql];
            uint4 v1 = X4[(size_t)s1 * 16 + ql];
            uint4 v2 = X4[(size_t)s2 * 16 + ql];
            uint4 v3 = X4[(size_t)s3 * 16 + ql];
            a0 += bflo(v0.x);               a1 += bfhi(v0.x);
            a2 += bflo(v0.y);               a3 += bfhi(v0.y);
            a4 += bflo(v0.z);               a5 += bfhi(v0.z);
            a6 += bflo(v0.w);               a7 += bfhi(v0.w);
            a0 = fmaf(w1, bflo(v1.x), a0);  a1 = fmaf(w1, bfhi(v1.x), a1);
            a2 = fmaf(w1, bflo(v1.y), a2);  a3 = fmaf(w1, bfhi(v1.y), a3);
            a4 = fmaf(w1, bflo(v1.z), a4);  a5 = fmaf(w1, bfhi(v1.z), a5);
            a6 = fmaf(w1, bflo(v1.w), a6);  a7 = fmaf(w1, bfhi(v1.w), a7);
            a0 = fmaf(w2, bflo(v2.x), a0);  a1 = fmaf(w2, bfhi(v2.x), a1);
            a2 = fmaf(w2, bflo(v2.y), a2);  a3 = fmaf(w2, bfhi(v2.y), a3);
            a4 = fmaf(w2, bflo(v2.z), a4);  a5 = fmaf(w2, bfhi(v2.z), a5);
            a6 = fmaf(w2, bflo(v2.w), a6);  a7 = fmaf(w2, bfhi(v2.w), a7);
            a0 = fmaf(w3, bflo(v3.x), a0);  a1 = fmaf(w3, bfhi(v3.x), a1);
            a2 = fmaf(w3, bflo(v3.y), a2);  a3 = fmaf(w3, bfhi(v3.y), a3);
            a4 = fmaf(w3, bflo(v3.z), a4);  a5 = fmaf(w3, bfhi(v3.z), a5);
            a6 = fmaf(w3, bflo(v3.w), a6);  a7 = fmaf(w3, bfhi(v3.w), a7);
        }
    }
    float sc = 1.0f / (float)(c > 0 ? c : 1);
    uint4 o;
    o.x = ((unsigned int)f2bf(a1 * sc) << 16) | (unsigned int)f2bf(a0 * sc);
    o.y = ((unsigned int)f2bf(a3 * sc) << 16) | (unsigned int)f2bf(a2 * sc);
    o.z = ((unsigned int)f2bf(a5 * sc) << 16) | (unsigned int)f2bf(a4 * sc);
    o.w = ((unsigned int)f2bf(a7 * sc) << 16) | (unsigned int)f2bf(a6 * sc);
    // wid*16+ql  ==  dst*48 + r*16 + ql  (wid = dst*3+r); wave writes 1KB contiguous
    ((uint4*)Abuf)[(size_t)wid * 16 + ql] = o;
}

// ---------- weight transpose ----------
template <int BN>
__global__ __launch_bounds__(256) void transpose_w(const float* __restrict__ Wrel,
                                                   const float* __restrict__ Wroot,
                                                   u16* __restrict__ Wt) {
    int idx = blockIdx.x * 256 + threadIdx.x;
    if (idx >= BN * 512) return;
    int n = idx >> 9;
    int k = idx & 511;
    float v = (k < 384) ? Wrel[(size_t)k * BN + n] : Wroot[(size_t)(k - 384) * BN + n];
    Wt[idx] = f2bf(v);
}

// ---------- fused GEMM ----------
template <int BN, bool RELU, bool OUTF32>
__global__ __launch_bounds__(256) void gemm_fused(const u16* __restrict__ Alo,
                                                  const u16* __restrict__ Ahi,
                                                  const u16* __restrict__ Wt,
                                                  const float* __restrict__ bias,
                                                  void* __restrict__ OutV) {
    constexpr int M = N_NODES;
    constexpr int BM = 128, BK = 32, KTOT = 512, KLO = 384;
    __shared__ __align__(16) u16 As[BM * BK];
    __shared__ __align__(16) u16 Bs[BN * BK];
    const int t = threadIdx.x;
    const int w = t >> 6, l = t & 63;
    const int bm = blockIdx.x * BM;
    constexpr int WN  = (BN == 128) ? 2 : 1;
    constexpr int WTM = (BN == 128) ? 64 : 32;
    constexpr int WTN = 64;
    constexpr int MI = WTM / 16, NI = WTN / 16;
    const int wm = w / WN, wn = w % WN;
    const int q = l >> 4, lm = l & 15;

    f32x4 acc[MI][NI] = {};

    const int ar = t >> 2;
    const int ac = (t & 3) * 8;

    for (int kt = 0; kt < KTOT / BK; ++kt) {
        const int k0 = kt * BK;
        const u16* base; int stride, kk;
        if (k0 < KLO) { base = Alo; stride = 384; kk = k0; }
        else          { base = Ahi; stride = 128; kk = k0 - KLO; }
        short8 va[2];
        #pragma unroll
        for (int i = 0; i < 2; ++i) {
            int gr = bm + i * 64 + ar; if (gr >= M) gr = M - 1;
            va[i] = *(const short8*)(base + (size_t)gr * stride + kk + ac);
        }
        short8 vb[BN / 64];
        #pragma unroll
        for (int i = 0; i < BN / 64; ++i) {
            int rn = i * 64 + ar;
            vb[i] = *(const short8*)(Wt + (size_t)rn * KTOT + k0 + ac);
        }
        __syncthreads();
        #pragma unroll
        for (int i = 0; i < 2; ++i)
            *(short8*)&As[(i * 64 + ar) * BK + ac] = va[i];
        #pragma unroll
        for (int i = 0; i < BN / 64; ++i)
            *(short8*)&Bs[(i * 64 + ar) * BK + ac] = vb[i];
        __syncthreads();
        short8 fa[MI], fb[NI];
        #pragma unroll
        for (int mi = 0; mi < MI; ++mi)
            fa[mi] = *(const short8*)&As[(wm * WTM + mi * 16 + lm) * BK + q * 8];
        #pragma unroll
        for (int ni = 0; ni < NI; ++ni)
            fb[ni] = *(const short8*)&Bs[(wn * WTN + ni * 16 + lm) * BK + q * 8];
        #pragma unroll
        for (int mi = 0; mi < MI; ++mi)
            #pragma unroll
            for (int ni = 0; ni < NI; ++ni)
                acc[mi][ni] = __builtin_amdgcn_mfma_f32_16x16x32_bf16(
                    fa[mi], fb[ni], acc[mi][ni], 0, 0, 0);
    }
    #pragma unroll
    for (int mi = 0; mi < MI; ++mi) {
        #pragma unroll
        for (int ni = 0; ni < NI; ++ni) {
            int gc = wn * WTN + ni * 16 + lm;
            float bv = bias[gc];
            #pragma unroll
            for (int rg = 0; rg < 4; ++rg) {
                int gr = bm + wm * WTM + mi * 16 + q * 4 + rg;
                if (gr < M) {
                    float v = acc[mi][ni][rg] + bv;
                    if (RELU) v = fmaxf(v, 0.0f);
                    if (OUTF32) ((float*)OutV)[(size_t)gr * BN + gc] = v;
                    else        ((u16*)OutV)[(size_t)gr * BN + gc] = f2bf(v);
                }
            }
        }
    }
}

// ---------- final pair MLP ----------
__global__ __launch_bounds__(128) void pair_mlp(const float* __restrict__ node,
                                                const int* __restrict__ nest,
                                                const int* __restrict__ food,
                                                const float* __restrict__ fcW,
                                                const float* __restrict__ fcb,
                                                float* __restrict__ out) {
    int p = blockIdx.x;
    int t = threadIdx.x;
    __shared__ float pv[128];
    int n0 = nest[p], n1 = food[p];
    if ((unsigned)n0 >= (unsigned)N_NODES) n0 = 0;
    if ((unsigned)n1 >= (unsigned)N_NODES) n1 = 0;
    if (t < 64) pv[t] = node[(size_t)n0 * 64 + t];
    else        pv[t] = node[(size_t)n1 * 64 + (t - 64)];
    __syncthreads();
    float s = fcb[t];
    #pragma unroll 4
    for (int k = 0; k < 128; ++k)
        s += pv[k] * fcW[k * 128 + t];
    out[(size_t)p * 128 + t] = tanhf(s);
}

extern "C" void kernel_launch(void* const* d_in, const int* in_sizes, int n_in,
                              void* d_out, int out_size, void* d_ws, size_t ws_size,
                              hipStream_t stream) {
    const float* x    = (const float*)d_in[0];
    const int* esrc   = (const int*)d_in[1];
    const int* edst   = (const int*)d_in[2];
    const int* etyp   = (const int*)d_in[3];
    const int* nest   = (const int*)d_in[5];
    const int* food   = (const int*)d_in[6];
    const float* Wrel1  = (const float*)d_in[7];
    const float* Wroot1 = (const float*)d_in[8];
    const float* b1     = (const float*)d_in[9];
    const float* Wrel2  = (const float*)d_in[10];
    const float* Wroot2 = (const float*)d_in[11];
    const float* b2     = (const float*)d_in[12];
    const float* fcW    = (const float*)d_in[13];
    const float* fcb    = (const float*)d_in[14];
    float* out = (float*)d_out;

    char* ws = (char*)d_ws;
    size_t off = 0;
    auto alloc_b = [&](size_t bytes) -> void* {
        void* p = ws + off;
        off += (bytes + 255) & ~(size_t)255;
        return p;
    };
    int* bc          = (int*)alloc_b((size_t)NBIN * NBLK * 4);
    int* sc          = (int*)alloc_b((size_t)NBIN * NBLK * 4);
    int* bt          = (int*)alloc_b((size_t)NBIN * 4);
    int* bb          = (int*)alloc_b((size_t)(NBIN + 1) * 4);
    unsigned int* bn = (unsigned int*)alloc_b((size_t)NEDGE * 4);
    int* seg_start   = (int*)alloc_b((size_t)NSEG * 4);
    int* cnt         = (int*)alloc_b((size_t)NSEG * 4);
    int* sorted_src  = (int*)alloc_b((size_t)NEDGE * 4);
    u16* Wt1         = (u16*)alloc_b((size_t)128 * 512 * 2);
    u16* Wt2         = (u16*)alloc_b((size_t)64 * 512 * 2);
    u16* xb          = (u16*)alloc_b((size_t)N_NODES * 128 * 2);
    u16* Abuf        = (u16*)alloc_b((size_t)N_NODES * 384 * 2);
    u16* h1          = (u16*)alloc_b((size_t)N_NODES * 128 * 2);
    float* node      = (float*)alloc_b((size_t)N_NODES * 64 * 4);

    // CSR build: binned counting sort (no global atomics)
    p1_count<<<NBLK, 256, 0, stream>>>(edst, bc);
    p2a_binscan<<<NBIN, 512, 0, stream>>>(bc, sc, bt);
    p2b_totscan<<<1, 256, 0, stream>>>(bt, bb);
    p3_binscatter<<<NBLK, 256, 0, stream>>>(esrc, edst, etyp, sc, bb, bn);
    p4_finalize<<<NBIN, 256, 0, stream>>>(bn, bb, seg_start, cnt, sorted_src);

    // weight transposes (f32 -> bf16 n-major)
    transpose_w<128><<<(128 * 512) / 256, 256, 0, stream>>>(Wrel1, Wroot1, Wt1);
    transpose_w<64><<<(64 * 512) / 256, 256, 0, stream>>>(Wrel2, Wroot2, Wt2);

    // cast x -> bf16 (gather source for layer-1 aggregation + GEMM A)
    cast_kernel<<<(N_NODES * 128 / 4 + 255) / 256, 256, 0, stream>>>(x, xb, N_NODES * 128 / 4);

    const int segBlocks  = NSEG / 16;                    // 18750 (4 segs/wave, 4 waves/block)
    const int gemmBlocks = (N_NODES + 127) / 128;        // 782

    // layer 1
    seg_mean<<<segBlocks, 256, 0, stream>>>((const uint4*)xb, seg_start, cnt, sorted_src, Abuf);
    gemm_fused<128, true, false><<<gemmBlocks, 256, 0, stream>>>(Abuf, xb, Wt1, b1, h1);

    // layer 2
    seg_mean<<<segBlocks, 256, 0, stream>>>((const uint4*)h1, seg_start, cnt, sorted_src, Abuf);
    gemm_fused<64, false, true><<<gemmBlocks, 256, 0, stream>>>(Abuf, h1, Wt2, b2, node);

    // pair MLP (f32)
    pair_mlp<<<NPAIR, 128, 0, stream>>>(node, nest, food, fcW, fcb, out);
}

// Round 11
// 396.178 us; speedup vs baseline: 1.6005x; 1.0043x over previous
//
#include <hip/hip_runtime.h>
#include <stdint.h>

typedef unsigned short u16;
typedef __attribute__((ext_vector_type(8))) short short8;
typedef __attribute__((ext_vector_type(4))) float f32x4;

#define N_NODES 100000
#define RREL    3
#define NEDGE   1600000
#define NPAIR   1024
#define NSEG    (RREL * N_NODES)

// binned CSR build params
#define EPB   4096
#define NBLK  ((NEDGE + EPB - 1) / EPB)   // 391
#define DPB   512                          // dsts per bin (dst >> 9)
#define NBIN  ((N_NODES + DPB - 1) / DPB)  // 196
#define LSEG  (DPB * RREL)                 // 1536 local segments per bin

// ---------- bf16 helpers ----------
__device__ __forceinline__ float bflo(unsigned int u) {
    union { unsigned int u; float f; } c; c.u = u << 16; return c.f;
}
__device__ __forceinline__ float bfhi(unsigned int u) {
    union { unsigned int u; float f; } c; c.u = u & 0xffff0000u; return c.f;
}
__device__ __forceinline__ u16 f2bf(float f) {
    union { float f; unsigned int u; } c; c.f = f;
    unsigned int u = c.u;
    u += 0x7fffu + ((u >> 16) & 1u);   // round-to-nearest-even
    return (u16)(u >> 16);
}

// ---------- async global->LDS, 16B per lane ----------
__device__ __forceinline__ void async_copy16(const u16* g, u16* l) {
    __builtin_amdgcn_global_load_lds(
        (const __attribute__((address_space(1))) unsigned int*)g,
        (__attribute__((address_space(3))) unsigned int*)l,
        16, 0, 0);
}

// ---------- cast f32 -> bf16, 4 elems/thread ----------
__global__ __launch_bounds__(256) void cast_kernel(const float* __restrict__ in,
                                                   u16* __restrict__ out, int n4) {
    int i = blockIdx.x * 256 + threadIdx.x;
    if (i >= n4) return;
    float4 v = ((const float4*)in)[i];
    uint2 o;
    o.x = ((unsigned int)f2bf(v.y) << 16) | (unsigned int)f2bf(v.x);
    o.y = ((unsigned int)f2bf(v.w) << 16) | (unsigned int)f2bf(v.z);
    ((uint2*)out)[i] = o;
}

// ========== CSR build: binned counting sort, no global atomics ==========

__global__ __launch_bounds__(256) void p1_count(const int* __restrict__ ed,
                                                int* __restrict__ bc) {
    __shared__ int h[NBIN];
    int t = threadIdx.x, b = blockIdx.x;
    for (int i = t; i < NBIN; i += 256) h[i] = 0;
    __syncthreads();
    int e0 = b * EPB;
    int e1 = e0 + EPB; if (e1 > NEDGE) e1 = NEDGE;
    for (int i = e0 + t; i < e1; i += 256)
        atomicAdd(&h[ed[i] >> 9], 1);
    __syncthreads();
    for (int i = t; i < NBIN; i += 256) bc[i * NBLK + b] = h[i];
}

__global__ __launch_bounds__(512) void p2a_binscan(const int* __restrict__ bc,
                                                   int* __restrict__ sc,
                                                   int* __restrict__ bt) {
    __shared__ int wtot[8];
    int t = threadIdx.x, bin = blockIdx.x;
    int v = (t < NBLK) ? bc[bin * NBLK + t] : 0;
    int lane = t & 63, wv = t >> 6;
    int incl = v;
    #pragma unroll
    for (int d = 1; d < 64; d <<= 1) { int u = __shfl_up(incl, d); if (lane >= d) incl += u; }
    if (lane == 63) wtot[wv] = incl;
    __syncthreads();
    int wpre = 0;
    #pragma unroll
    for (int i = 0; i < 8; ++i) if (i < wv) wpre += wtot[i];
    if (t < NBLK) sc[bin * NBLK + t] = wpre + incl - v;
    if (t == 511) bt[bin] = wpre + incl;
}

__global__ __launch_bounds__(256) void p2b_totscan(const int* __restrict__ bt,
                                                   int* __restrict__ bb) {
    __shared__ int wtot[4];
    int t = threadIdx.x;
    int v = (t < NBIN) ? bt[t] : 0;
    int lane = t & 63, wv = t >> 6;
    int incl = v;
    #pragma unroll
    for (int d = 1; d < 64; d <<= 1) { int u = __shfl_up(incl, d); if (lane >= d) incl += u; }
    if (lane == 63) wtot[wv] = incl;
    __syncthreads();
    int wpre = 0;
    #pragma unroll
    for (int i = 0; i < 4; ++i) if (i < wv) wpre += wtot[i];
    if (t < NBIN) bb[t] = wpre + incl - v;
    if (t == 0) bb[NBIN] = NEDGE;
}

__global__ __launch_bounds__(256) void p3_binscatter(const int* __restrict__ es,
                                                     const int* __restrict__ ed,
                                                     const int* __restrict__ et,
                                                     const int* __restrict__ sc,
                                                     const int* __restrict__ bb,
                                                     unsigned int* __restrict__ binned) {
    __shared__ int pos[NBIN];
    int t = threadIdx.x, b = blockIdx.x;
    for (int i = t; i < NBIN; i += 256) pos[i] = bb[i] + sc[i * NBLK + b];
    __syncthreads();
    int e0 = b * EPB;
    int e1 = e0 + EPB; if (e1 > NEDGE) e1 = NEDGE;
    for (int i = e0 + t; i < e1; i += 256) {
        int d = ed[i];
        int bin = d >> 9;
        unsigned int pk = ((unsigned int)es[i] << 11) | (unsigned int)((d & 511) * 3 + et[i]);
        int p = atomicAdd(&pos[bin], 1);
        binned[p] = pk;
    }
}

__global__ __launch_bounds__(256) void p4_finalize(const unsigned int* __restrict__ binned,
                                                   const int* __restrict__ bb,
                                                   int* __restrict__ seg_start,
                                                   int* __restrict__ cnt,
                                                   int* __restrict__ sorted_src) {
    __shared__ int h[LSEG];
    __shared__ int cur[LSEG];
    __shared__ int wtot4[4];
    int t = threadIdx.x, bin = blockIdx.x;
    for (int i = t; i < LSEG; i += 256) h[i] = 0;
    __syncthreads();
    int eb = bb[bin];
    int ee = bb[bin + 1];
    for (int i = eb + t; i < ee; i += 256)
        atomicAdd(&h[binned[i] & 2047u], 1);
    __syncthreads();
    int i6 = t * 6;
    int s = 0;
    #pragma unroll
    for (int i = 0; i < 6; ++i) s += h[i6 + i];
    int lane = t & 63, wv = t >> 6;
    int incl = s;
    #pragma unroll
    for (int d = 1; d < 64; d <<= 1) { int v = __shfl_up(incl, d); if (lane >= d) incl += v; }
    if (lane == 63) wtot4[wv] = incl;
    __syncthreads();
    int wpre = 0;
    #pragma unroll
    for (int i = 0; i < 4; ++i) if (i < wv) wpre += wtot4[i];
    int run = wpre + incl - s;
    int segbase = bin * LSEG;
    #pragma unroll
    for (int i = 0; i < 6; ++i) {
        int ls = i6 + i;
        int c = h[ls];
        int seg = segbase + ls;
        if (seg < NSEG) { seg_start[seg] = eb + run; cnt[seg] = c; }
        cur[ls] = run;
        run += c;
    }
    __syncthreads();
    for (int i = eb + t; i < ee; i += 256) {
        unsigned int u = binned[i];
        int ls = (int)(u & 2047u);
        int p = atomicAdd(&cur[ls], 1);
        sorted_src[eb + p] = (int)(u >> 11);
    }
}

// ---------- per-segment mean; one QUARTER-WAVE per segment (wave = 4 segs) ----------
__global__ __launch_bounds__(256) void seg_mean(const uint4* __restrict__ X4,  // (N,16) uint4 = bf16x8
                                                const int* __restrict__ seg_start,
                                                const int* __restrict__ cnt,
                                                const int* __restrict__ sorted_src,
                                                u16* __restrict__ Abuf) {
    int lane = threadIdx.x & 63;
    int q4 = lane >> 4, ql = lane & 15;
    int wid = ((blockIdx.x * 256 + threadIdx.x) >> 6) * 4 + q4;   // NSEG % 4 == 0
    if (wid >= NSEG) return;
    int c  = cnt[wid];
    int st = seg_start[wid];

    float a0 = 0.f, a1 = 0.f, a2 = 0.f, a3 = 0.f,
          a4 = 0.f, a5 = 0.f, a6 = 0.f, a7 = 0.f;

    int shbase = q4 * 16;
    for (int base = 0; base < c; base += 16) {
        int rem = c - base;                       // >= 1
        int ii  = (ql < rem) ? ql : (rem - 1);
        int idxv = sorted_src[st + base + ii];    // idx for edge base+ql (clamped)
        int lim = (rem < 16) ? rem : 16;
        for (int j = 0; j < lim; j += 4) {
            int e1 = j + 1, e2 = j + 2, e3 = j + 3;
            float w1 = (e1 < lim) ? 1.f : 0.f;
            float w2 = (e2 < lim) ? 1.f : 0.f;
            float w3 = (e3 < lim) ? 1.f : 0.f;
            int s0 = __shfl(idxv, shbase + j);
            int s1 = __shfl(idxv, shbase + ((e1 < lim) ? e1 : 0));
            int s2 = __shfl(idxv, shbase + ((e2 < lim) ? e2 : 0));
            int s3 = __shfl(idxv, shbase + ((e3 < lim) ? e3 : 0));
            uint4 v0 = X4[(size_t)s0 * 16 + ql];
            uint4 v1 = X4[(size_t)s1 * 16 + ql];
            uint4 v2 = X4[(size_t)s2 * 16 + ql];
            uint4 v3 = X4[(size_t)s3 * 16 + ql];
            a0 += bflo(v0.x);               a1 += bfhi(v0.x);
            a2 += bflo(v0.y);               a3 += bfhi(v0.y);
            a4 += bflo(v0.z);               a5 += bfhi(v0.z);
            a6 += bflo(v0.w);               a7 += bfhi(v0.w);
            a0 = fmaf(w1, bflo(v1.x), a0);  a1 = fmaf(w1, bfhi(v1.x), a1);
            a2 = fmaf(w1, bflo(v1.y), a2);  a3 = fmaf(w1, bfhi(v1.y), a3);
            a4 = fmaf(w1, bflo(v1.z), a4);  a5 = fmaf(w1, bfhi(v1.z), a5);
            a6 = fmaf(w1, bflo(v1.w), a6);  a7 = fmaf(w1, bfhi(v1.w), a7);
            a0 = fmaf(w2, bflo(v2.x), a0);  a1 = fmaf(w2, bfhi(v2.x), a1);
            a2 = fmaf(w2, bflo(v2.y), a2);  a3 = fmaf(w2, bfhi(v2.y), a3);
            a4 = fmaf(w2, bflo(v2.z), a4);  a5 = fmaf(w2, bfhi(v2.z), a5);
            a6 = fmaf(w2, bflo(v2.w), a6);  a7 = fmaf(w2, bfhi(v2.w), a7);
            a0 = fmaf(w3, bflo(v3.x), a0);  a1 = fmaf(w3, bfhi(v3.x), a1);
            a2 = fmaf(w3, bflo(v3.y), a2);  a3 = fmaf(w3, bfhi(v3.y), a3);
            a4 = fmaf(w3, bflo(v3.z), a4);  a5 = fmaf(w3, bfhi(v3.z), a5);
            a6 = fmaf(w3, bflo(v3.w), a6);  a7 = fmaf(w3, bfhi(v3.w), a7);
        }
    }
    float sc = 1.0f / (float)(c > 0 ? c : 1);
    uint4 o;
    o.x = ((unsigned int)f2bf(a1 * sc) << 16) | (unsigned int)f2bf(a0 * sc);
    o.y = ((unsigned int)f2bf(a3 * sc) << 16) | (unsigned int)f2bf(a2 * sc);
    o.z = ((unsigned int)f2bf(a5 * sc) << 16) | (unsigned int)f2bf(a4 * sc);
    o.w = ((unsigned int)f2bf(a7 * sc) << 16) | (unsigned int)f2bf(a6 * sc);
    ((uint4*)Abuf)[(size_t)wid * 16 + ql] = o;
}

// ---------- merged weight transpose: Wt1 (128x512) + Wt2 (64x512), n-major bf16 ----------
__global__ __launch_bounds__(256) void transpose_w_all(const float* __restrict__ Wrel1,
                                                       const float* __restrict__ Wroot1,
                                                       const float* __restrict__ Wrel2,
                                                       const float* __restrict__ Wroot2,
                                                       u16* __restrict__ Wt1,
                                                       u16* __restrict__ Wt2) {
    int idx = blockIdx.x * 256 + threadIdx.x;
    if (idx < 128 * 512) {
        int n = idx >> 9, k = idx & 511;
        float v = (k < 384) ? Wrel1[(size_t)k * 128 + n] : Wroot1[(size_t)(k - 384) * 128 + n];
        Wt1[idx] = f2bf(v);
    } else {
        int j = idx - 128 * 512;
        if (j < 64 * 512) {
            int n = j >> 9, k = j & 511;
            float v = (k < 384) ? Wrel2[(size_t)k * 64 + n] : Wroot2[(size_t)(k - 384) * 64 + n];
            Wt2[j] = f2bf(v);
        }
    }
}

// ---------- fused GEMM: async global_load_lds staging (m97 pattern) ----------
template <int BN, bool RELU, bool OUTF32>
__global__ __launch_bounds__(256) void gemm_fused(const u16* __restrict__ Alo,
                                                  const u16* __restrict__ Ahi,
                                                  const u16* __restrict__ Wt,
                                                  const float* __restrict__ bias,
                                                  void* __restrict__ OutV) {
    constexpr int M = N_NODES;
    constexpr int BM = 128, BK = 32, KTOT = 512, KLO = 384;
    __shared__ __align__(16) u16 As[BM * BK];
    __shared__ __align__(16) u16 Bs[BN * BK];
    const int t = threadIdx.x;
    const int w = t >> 6, l = t & 63;
    const int bm = blockIdx.x * BM;
    constexpr int WN  = (BN == 128) ? 2 : 1;
    constexpr int WTM = (BN == 128) ? 64 : 32;
    constexpr int WTN = 64;
    constexpr int MI = WTM / 16, NI = WTN / 16;
    const int wm = w / WN, wn = w % WN;
    const int q = l >> 4, lm = l & 15;

    f32x4 acc[MI][NI] = {};

    const int ar = t >> 2;            // 0..63
    const int ac = (t & 3) * 8;       // 0,8,16,24
    // LDS dest for thread t in row-major (r*BK+c) layout = 16B * t within each
    // 64-row chunk -> satisfies wave-uniform base + lane*16 requirement.

    // precompute clamped A row pointers (rows fixed across K tiles)
    int gr0 = bm + ar;       if (gr0 >= M) gr0 = M - 1;
    int gr1 = bm + 64 + ar;  if (gr1 >= M) gr1 = M - 1;

    for (int kt = 0; kt < KTOT / BK; ++kt) {
        const int k0 = kt * BK;
        const u16* base; int stride, kk;
        if (k0 < KLO) { base = Alo; stride = 384; kk = k0; }
        else          { base = Ahi; stride = 128; kk = k0 - KLO; }
        __syncthreads();   // previous iteration done reading LDS
        async_copy16(base + (size_t)gr0 * stride + kk + ac, &As[ar * BK + ac]);
        async_copy16(base + (size_t)gr1 * stride + kk + ac, &As[(64 + ar) * BK + ac]);
        #pragma unroll
        for (int i = 0; i < BN / 64; ++i)
            async_copy16(Wt + (size_t)(i * 64 + ar) * KTOT + k0 + ac,
                         &Bs[(i * 64 + ar) * BK + ac]);
        __syncthreads();   // drains vmcnt before LDS reads
        short8 fa[MI], fb[NI];
        #pragma unroll
        for (int mi = 0; mi < MI; ++mi)
            fa[mi] = *(const short8*)&As[(wm * WTM + mi * 16 + lm) * BK + q * 8];
        #pragma unroll
        for (int ni = 0; ni < NI; ++ni)
            fb[ni] = *(const short8*)&Bs[(wn * WTN + ni * 16 + lm) * BK + q * 8];
        #pragma unroll
        for (int mi = 0; mi < MI; ++mi)
            #pragma unroll
            for (int ni = 0; ni < NI; ++ni)
                acc[mi][ni] = __builtin_amdgcn_mfma_f32_16x16x32_bf16(
                    fa[mi], fb[ni], acc[mi][ni], 0, 0, 0);
    }
    // epilogue: C/D layout col=lane&15, row=q*4+reg
    #pragma unroll
    for (int mi = 0; mi < MI; ++mi) {
        #pragma unroll
        for (int ni = 0; ni < NI; ++ni) {
            int gc = wn * WTN + ni * 16 + lm;
            float bv = bias[gc];
            #pragma unroll
            for (int rg = 0; rg < 4; ++rg) {
                int gr = bm + wm * WTM + mi * 16 + q * 4 + rg;
                if (gr < M) {
                    float v = acc[mi][ni][rg] + bv;
                    if (RELU) v = fmaxf(v, 0.0f);
                    if (OUTF32) ((float*)OutV)[(size_t)gr * BN + gc] = v;
                    else        ((u16*)OutV)[(size_t)gr * BN + gc] = f2bf(v);
                }
            }
        }
    }
}

// ---------- final pair MLP ----------
__global__ __launch_bounds__(128) void pair_mlp(const float* __restrict__ node,
                                                const int* __restrict__ nest,
                                                const int* __restrict__ food,
                                                const float* __restrict__ fcW,
                                                const float* __restrict__ fcb,
                                                float* __restrict__ out) {
    int p = blockIdx.x;
    int t = threadIdx.x;
    __shared__ float pv[128];
    int n0 = nest[p], n1 = food[p];
    if ((unsigned)n0 >= (unsigned)N_NODES) n0 = 0;
    if ((unsigned)n1 >= (unsigned)N_NODES) n1 = 0;
    if (t < 64) pv[t] = node[(size_t)n0 * 64 + t];
    else        pv[t] = node[(size_t)n1 * 64 + (t - 64)];
    __syncthreads();
    float s = fcb[t];
    #pragma unroll 4
    for (int k = 0; k < 128; ++k)
        s += pv[k] * fcW[k * 128 + t];
    out[(size_t)p * 128 + t] = tanhf(s);
}

extern "C" void kernel_launch(void* const* d_in, const int* in_sizes, int n_in,
                              void* d_out, int out_size, void* d_ws, size_t ws_size,
                              hipStream_t stream) {
    const float* x    = (const float*)d_in[0];
    const int* esrc   = (const int*)d_in[1];
    const int* edst   = (const int*)d_in[2];
    const int* etyp   = (const int*)d_in[3];
    const int* nest   = (const int*)d_in[5];
    const int* food   = (const int*)d_in[6];
    const float* Wrel1  = (const float*)d_in[7];
    const float* Wroot1 = (const float*)d_in[8];
    const float* b1     = (const float*)d_in[9];
    const float* Wrel2  = (const float*)d_in[10];
    const float* Wroot2 = (const float*)d_in[11];
    const float* b2     = (const float*)d_in[12];
    const float* fcW    = (const float*)d_in[13];
    const float* fcb    = (const float*)d_in[14];
    float* out = (float*)d_out;

    char* ws = (char*)d_ws;
    size_t off = 0;
    auto alloc_b = [&](size_t bytes) -> void* {
        void* p = ws + off;
        off += (bytes + 255) & ~(size_t)255;
        return p;
    };
    int* bc          = (int*)alloc_b((size_t)NBIN * NBLK * 4);
    int* sc          = (int*)alloc_b((size_t)NBIN * NBLK * 4);
    int* bt          = (int*)alloc_b((size_t)NBIN * 4);
    int* bb          = (int*)alloc_b((size_t)(NBIN + 1) * 4);
    unsigned int* bn = (unsigned int*)alloc_b((size_t)NEDGE * 4);
    int* seg_start   = (int*)alloc_b((size_t)NSEG * 4);
    int* cnt         = (int*)alloc_b((size_t)NSEG * 4);
    int* sorted_src  = (int*)alloc_b((size_t)NEDGE * 4);
    u16* Wt1         = (u16*)alloc_b((size_t)128 * 512 * 2);
    u16* Wt2         = (u16*)alloc_b((size_t)64 * 512 * 2);
    u16* xb          = (u16*)alloc_b((size_t)N_NODES * 128 * 2);
    u16* Abuf        = (u16*)alloc_b((size_t)N_NODES * 384 * 2);
    u16* h1          = (u16*)alloc_b((size_t)N_NODES * 128 * 2);
    float* node      = (float*)alloc_b((size_t)N_NODES * 64 * 4);

    // CSR build: binned counting sort (no global atomics)
    p1_count<<<NBLK, 256, 0, stream>>>(edst, bc);
    p2a_binscan<<<NBIN, 512, 0, stream>>>(bc, sc, bt);
    p2b_totscan<<<1, 256, 0, stream>>>(bt, bb);
    p3_binscatter<<<NBLK, 256, 0, stream>>>(esrc, edst, etyp, sc, bb, bn);
    p4_finalize<<<NBIN, 256, 0, stream>>>(bn, bb, seg_start, cnt, sorted_src);

    // merged weight transpose (f32 -> bf16 n-major)
    transpose_w_all<<<(192 * 512) / 256, 256, 0, stream>>>(Wrel1, Wroot1, Wrel2, Wroot2, Wt1, Wt2);

    // cast x -> bf16 (gather source for layer-1 aggregation + GEMM A)
    cast_kernel<<<(N_NODES * 128 / 4 + 255) / 256, 256, 0, stream>>>(x, xb, N_NODES * 128 / 4);

    const int segBlocks  = NSEG / 16;                    // 18750 (4 segs/wave, 4 waves/block)
    const int gemmBlocks = (N_NODES + 127) / 128;        // 782

    // layer 1
    seg_mean<<<segBlocks, 256, 0, stream>>>((const uint4*)xb, seg_start, cnt, sorted_src, Abuf);
    gemm_fused<128, true, false><<<gemmBlocks, 256, 0, stream>>>(Abuf, xb, Wt1, b1, h1);

    // layer 2
    seg_mean<<<segBlocks, 256, 0, stream>>>((const uint4*)h1, seg_start, cnt, sorted_src, Abuf);
    gemm_fused<64, false, true><<<gemmBlocks, 256, 0, stream>>>(Abuf, h1, Wt2, b2, node);

    // pair MLP (f32)
    pair_mlp<<<NPAIR, 128, 0, stream>>>(node, nest, food, fcW, fcb, out);
}